// Round 3
// baseline (352.365 us; speedup 1.0000x reference)
//
#include <hip/hip_runtime.h>
#include <stdint.h>

#define B_ 2
#define S_ 1024
#define D_ 768
#define NH_ 12
#define DH_ 64
#define HID_ 1536
#define G_ 4
#define EPG_ 2
#define E_ 8
#define NTOK (B_*S_)

typedef unsigned short u16;
typedef __bf16 bf16x8 __attribute__((ext_vector_type(8)));
typedef float f32x4 __attribute__((ext_vector_type(4)));
typedef u16 u16x4 __attribute__((ext_vector_type(4)));
typedef u16 u16x8 __attribute__((ext_vector_type(8)));

struct BfPair { u16 hi, lo; };

__device__ __forceinline__ u16 f2bf(float f){
  unsigned u = __builtin_bit_cast(unsigned, f);
  u += 0x7FFFu + ((u >> 16) & 1u);
  return (u16)(u >> 16);
}
__device__ __forceinline__ float bf2f(u16 h){
  unsigned u = ((unsigned)h) << 16;
  return __builtin_bit_cast(float, u);
}
__device__ __forceinline__ BfPair split_bf(float v){
  BfPair p;
  p.hi = f2bf(v);
  p.lo = f2bf(v - bf2f(p.hi));
  return p;
}
__device__ __forceinline__ float gelu_tanh(float x){
  float t = 0.7978845608028654f * (x + 0.044715f * x * x * x);
  float e = __expf(2.f * t);
  float th = 1.f - 2.f / (e + 1.f);
  return 0.5f * x * (1.f + th);
}
__device__ __forceinline__ void gload_lds16(const void* g, void* l){
  __builtin_amdgcn_global_load_lds(
      (const __attribute__((address_space(1))) void*)g,
      (__attribute__((address_space(3))) void*)l, 16, 0, 0);
}

// ---------------- convert+split f32 -> (bf16 hi, bf16 lo) ----------------
__global__ void k_convert_split(const float* __restrict__ src, u16* __restrict__ dh,
                                u16* __restrict__ dl, int n4){
  int i = blockIdx.x * blockDim.x + threadIdx.x;
  if (i < n4){
    float4 v = ((const float4*)src)[i];
    u16x4 oh, ol;
    BfPair p0 = split_bf(v.x), p1 = split_bf(v.y), p2 = split_bf(v.z), p3 = split_bf(v.w);
    oh.x = p0.hi; ol.x = p0.lo;
    oh.y = p1.hi; ol.y = p1.lo;
    oh.z = p2.hi; ol.z = p2.lo;
    oh.w = p3.hi; ol.w = p3.lo;
    ((u16x4*)dh)[i] = oh;
    ((u16x4*)dl)[i] = ol;
  }
}

// ---------------- tiled transpose + convert: src [E][R][C] f32 -> dst [E][C][R] bf16 ----
__global__ void k_transpose_bf16(const float* __restrict__ src, u16* __restrict__ dst, int R, int C){
  __shared__ float tile[32][33];
  int e = blockIdx.z;
  const float* s = src + (size_t)e * R * C;
  u16* d = dst + (size_t)e * R * C;
  int c0 = blockIdx.x * 32, r0 = blockIdx.y * 32;
  #pragma unroll
  for (int i = 0; i < 32; i += 8)
    tile[threadIdx.y + i][threadIdx.x] = s[(size_t)(r0 + threadIdx.y + i) * C + c0 + threadIdx.x];
  __syncthreads();
  #pragma unroll
  for (int i = 0; i < 32; i += 8)
    d[(size_t)(c0 + threadIdx.y + i) * R + r0 + threadIdx.x] = f2bf(tile[threadIdx.x][threadIdx.y + i]);
}

// ---------------- V transpose: qkv hi/lo [N][2304] -> vt hi/lo [BH][64][1024] ----------
__global__ void k_transpose_v(const u16* __restrict__ qh, const u16* __restrict__ ql,
                              u16* __restrict__ vth, u16* __restrict__ vtl){
  __shared__ u16 th[32][34], tl[32][34];
  int bh = blockIdx.z, b = bh / NH_, h = bh % NH_;
  int d0 = blockIdx.x * 32, s0 = blockIdx.y * 32;
  #pragma unroll
  for (int i = 0; i < 32; i += 8){
    size_t src = (size_t)(b * S_ + s0 + threadIdx.y + i) * (3 * D_) + 2 * D_ + h * DH_ + d0 + threadIdx.x;
    th[threadIdx.y + i][threadIdx.x] = qh[src];
    tl[threadIdx.y + i][threadIdx.x] = ql[src];
  }
  __syncthreads();
  #pragma unroll
  for (int i = 0; i < 32; i += 8){
    size_t dst = ((size_t)bh * DH_ + d0 + threadIdx.y + i) * S_ + s0 + threadIdx.x;
    vth[dst] = th[threadIdx.x][threadIdx.y + i];
    vtl[dst] = tl[threadIdx.x][threadIdx.y + i];
  }
}

// ---------------- layernorm: f32 in -> bf16 hi (+lo) (+f32) ----------------
__global__ __launch_bounds__(256) void k_layernorm(
    const float* __restrict__ x, const float* __restrict__ w, const float* __restrict__ b,
    u16* __restrict__ oh, u16* __restrict__ ol, float* __restrict__ of){
  int row = blockIdx.x;
  const float* xr = x + (size_t)row * D_;
  int t = threadIdx.x;
  float v0 = xr[t], v1 = xr[t + 256], v2 = xr[t + 512];
  float s = v0 + v1 + v2;
  float sq = v0 * v0 + v1 * v1 + v2 * v2;
  #pragma unroll
  for (int m = 1; m < 64; m <<= 1){ s += __shfl_xor(s, m); sq += __shfl_xor(sq, m); }
  __shared__ float ls[4], lq[4];
  int wid = t >> 6;
  if ((t & 63) == 0){ ls[wid] = s; lq[wid] = sq; }
  __syncthreads();
  s = ls[0] + ls[1] + ls[2] + ls[3];
  sq = lq[0] + lq[1] + lq[2] + lq[3];
  float mean = s * (1.f / D_);
  float var = sq * (1.f / D_) - mean * mean;
  float rstd = rsqrtf(var + 1e-5f);
  #pragma unroll
  for (int i = 0; i < 3; i++){
    int dcol = t + i * 256;
    float v = (i == 0 ? v0 : (i == 1 ? v1 : v2));
    float y = (v - mean) * rstd * w[dcol] + b[dcol];
    BfPair p = split_bf(y);
    oh[(size_t)row * D_ + dcol] = p.hi;
    if (ol) ol[(size_t)row * D_ + dcol] = p.lo;
    if (of) of[(size_t)row * D_ + dcol] = y;
  }
}

// ---------------- split-precision GEMM: C = (Ah+Al) @ (Bh+Bl)^T + bias ----------------
// EPI 0: store split bf16 (outh,outl). EPI 1: store f32 + resid.
template<int EPI>
__global__ __launch_bounds__(256) void k_gemm3(
    const u16* __restrict__ Ah, const u16* __restrict__ Al,
    const u16* __restrict__ Bh, const u16* __restrict__ Bl,
    const float* __restrict__ bias, const float* __restrict__ resid,
    u16* __restrict__ outh, u16* __restrict__ outl, float* __restrict__ outf,
    int M, int N, int K){
  __shared__ alignas(16) u16 Ash[128 * 32];
  __shared__ alignas(16) u16 Asl[128 * 32];
  __shared__ alignas(16) u16 Bsh[128 * 32];
  __shared__ alignas(16) u16 Bsl[128 * 32];
  int m0 = blockIdx.x * 128, n0 = blockIdx.y * 128;
  int tid = threadIdx.x, w = tid >> 6, l = tid & 63;
  int wr = w >> 1, wc = w & 1;
  f32x4 acc[4][4];
  #pragma unroll
  for (int i = 0; i < 4; i++)
    #pragma unroll
    for (int j = 0; j < 4; j++) acc[i][j] = f32x4{0.f, 0.f, 0.f, 0.f};
  int sr = w * 32 + (l >> 2);
  int kch = (l & 3) * 8;
  size_t aoff = (size_t)(m0 + sr) * K + kch;
  size_t boff = (size_t)(n0 + sr) * K + kch;
  const u16* Agh0 = Ah + aoff; const u16* Agh1 = Agh0 + (size_t)16 * K;
  const u16* Agl0 = Al + aoff; const u16* Agl1 = Agl0 + (size_t)16 * K;
  const u16* Bgh0 = Bh + boff; const u16* Bgh1 = Bgh0 + (size_t)16 * K;
  const u16* Bgl0 = Bl + boff; const u16* Bgl1 = Bgl0 + (size_t)16 * K;
  u16* AshD0 = &Ash[(w * 32) * 32]; u16* AshD1 = &Ash[(w * 32 + 16) * 32];
  u16* AslD0 = &Asl[(w * 32) * 32]; u16* AslD1 = &Asl[(w * 32 + 16) * 32];
  u16* BshD0 = &Bsh[(w * 32) * 32]; u16* BshD1 = &Bsh[(w * 32 + 16) * 32];
  u16* BslD0 = &Bsl[(w * 32) * 32]; u16* BslD1 = &Bsl[(w * 32 + 16) * 32];
  for (int k0 = 0; k0 < K; k0 += 32){
    __syncthreads();
    gload_lds16(Agh0 + k0, AshD0); gload_lds16(Agh1 + k0, AshD1);
    gload_lds16(Agl0 + k0, AslD0); gload_lds16(Agl1 + k0, AslD1);
    gload_lds16(Bgh0 + k0, BshD0); gload_lds16(Bgh1 + k0, BshD1);
    gload_lds16(Bgl0 + k0, BslD0); gload_lds16(Bgl1 + k0, BslD1);
    __syncthreads();
    bf16x8 afh[4], afl[4], bfh[4], bfl[4];
    #pragma unroll
    for (int mi = 0; mi < 4; mi++){
      int idx = (wr * 64 + mi * 16 + (l & 15)) * 32 + 8 * (l >> 4);
      afh[mi] = *(const bf16x8*)&Ash[idx];
      afl[mi] = *(const bf16x8*)&Asl[idx];
    }
    #pragma unroll
    for (int ni = 0; ni < 4; ni++){
      int idx = (wc * 64 + ni * 16 + (l & 15)) * 32 + 8 * (l >> 4);
      bfh[ni] = *(const bf16x8*)&Bsh[idx];
      bfl[ni] = *(const bf16x8*)&Bsl[idx];
    }
    #pragma unroll
    for (int mi = 0; mi < 4; mi++)
      #pragma unroll
      for (int ni = 0; ni < 4; ni++){
        acc[mi][ni] = __builtin_amdgcn_mfma_f32_16x16x32_bf16(afh[mi], bfh[ni], acc[mi][ni], 0, 0, 0);
        acc[mi][ni] = __builtin_amdgcn_mfma_f32_16x16x32_bf16(afh[mi], bfl[ni], acc[mi][ni], 0, 0, 0);
        acc[mi][ni] = __builtin_amdgcn_mfma_f32_16x16x32_bf16(afl[mi], bfh[ni], acc[mi][ni], 0, 0, 0);
      }
  }
  int r4 = (l >> 4) * 4, cc = l & 15;
  #pragma unroll
  for (int mi = 0; mi < 4; mi++){
    #pragma unroll
    for (int ni = 0; ni < 4; ni++){
      int col = n0 + wc * 64 + ni * 16 + cc;
      float bv = bias ? bias[col] : 0.f;
      #pragma unroll
      for (int r = 0; r < 4; r++){
        int row = m0 + wr * 64 + mi * 16 + r4 + r;
        float v = acc[mi][ni][r] + bv;
        if (EPI == 0){
          BfPair p = split_bf(v);
          outh[(size_t)row * N + col] = p.hi;
          outl[(size_t)row * N + col] = p.lo;
        } else {
          outf[(size_t)row * N + col] = v + resid[(size_t)row * N + col];
        }
      }
    }
  }
}

// ---------------- split-precision flash attention ----------------
__global__ __launch_bounds__(256) void k_attn3(
    const u16* __restrict__ qkvh, const u16* __restrict__ qkvl,
    const u16* __restrict__ vth, const u16* __restrict__ vtl,
    u16* __restrict__ oh, u16* __restrict__ ol){
  __shared__ alignas(16) u16 Ksh[64 * 64];
  __shared__ alignas(16) u16 Ksl[64 * 64];
  __shared__ alignas(16) u16 Vsh[64 * 64];
  __shared__ alignas(16) u16 Vsl[64 * 64];
  __shared__ alignas(16) u16 Ph[4 * 16 * 64];
  __shared__ alignas(16) u16 Pl[4 * 16 * 64];
  int bh = blockIdx.y;
  int b = bh / NH_, h = bh % NH_;
  int qb = blockIdx.x;
  int tid = threadIdx.x, w = tid >> 6, l = tid & 63;
  int q0 = qb * 64 + w * 16;
  const int RS = 3 * D_;
  size_t qoff = (size_t)(b * S_ + q0 + (l & 15)) * RS + h * DH_ + 8 * (l >> 4);
  bf16x8 aqh[2], aql[2];
  aqh[0] = *(const bf16x8*)(qkvh + qoff); aqh[1] = *(const bf16x8*)(qkvh + qoff + 32);
  aql[0] = *(const bf16x8*)(qkvl + qoff); aql[1] = *(const bf16x8*)(qkvl + qoff + 32);
  f32x4 oacc[4];
  #pragma unroll
  for (int i = 0; i < 4; i++) oacc[i] = f32x4{0.f, 0.f, 0.f, 0.f};
  float mrun[4], lrun[4];
  #pragma unroll
  for (int r = 0; r < 4; r++){ mrun[r] = -1e30f; lrun[r] = 0.f; }

  size_t koff = (size_t)(b * S_ + w * 16 + (l >> 3)) * RS + D_ + h * DH_ + (l & 7) * 8;
  const u16* Kgh = qkvh + koff;
  const u16* Kgl = qkvl + koff;
  size_t voff = ((size_t)bh * DH_ + w * 16 + (l >> 3)) * S_ + (l & 7) * 8;
  const u16* Vgh = vth + voff;
  const u16* Vgl = vtl + voff;
  u16* KshD0 = &Ksh[(w * 16) * 64]; u16* KshD1 = &Ksh[(w * 16 + 8) * 64];
  u16* KslD0 = &Ksl[(w * 16) * 64]; u16* KslD1 = &Ksl[(w * 16 + 8) * 64];
  u16* VshD0 = &Vsh[(w * 16) * 64]; u16* VshD1 = &Vsh[(w * 16 + 8) * 64];
  u16* VslD0 = &Vsl[(w * 16) * 64]; u16* VslD1 = &Vsl[(w * 16 + 8) * 64];

  for (int kt = 0; kt < S_ / 64; kt++){
    __syncthreads();
    gload_lds16(Kgh + (size_t)(kt * 64) * RS, KshD0);
    gload_lds16(Kgh + (size_t)(kt * 64 + 8) * RS, KshD1);
    gload_lds16(Kgl + (size_t)(kt * 64) * RS, KslD0);
    gload_lds16(Kgl + (size_t)(kt * 64 + 8) * RS, KslD1);
    gload_lds16(Vgh + kt * 64, VshD0);
    gload_lds16(Vgh + kt * 64 + 8 * S_, VshD1);
    gload_lds16(Vgl + kt * 64, VslD0);
    gload_lds16(Vgl + kt * 64 + 8 * S_, VslD1);
    __syncthreads();
    // QK^T (3-term split)
    f32x4 st[4];
    #pragma unroll
    for (int nt = 0; nt < 4; nt++){
      int idx = (nt * 16 + (l & 15)) * 64 + 8 * (l >> 4);
      bf16x8 kh0 = *(const bf16x8*)&Ksh[idx];
      bf16x8 kh1 = *(const bf16x8*)&Ksh[idx + 32];
      bf16x8 kl0 = *(const bf16x8*)&Ksl[idx];
      bf16x8 kl1 = *(const bf16x8*)&Ksl[idx + 32];
      f32x4 c = f32x4{0.f, 0.f, 0.f, 0.f};
      c = __builtin_amdgcn_mfma_f32_16x16x32_bf16(aqh[0], kh0, c, 0, 0, 0);
      c = __builtin_amdgcn_mfma_f32_16x16x32_bf16(aqh[1], kh1, c, 0, 0, 0);
      c = __builtin_amdgcn_mfma_f32_16x16x32_bf16(aqh[0], kl0, c, 0, 0, 0);
      c = __builtin_amdgcn_mfma_f32_16x16x32_bf16(aqh[1], kl1, c, 0, 0, 0);
      c = __builtin_amdgcn_mfma_f32_16x16x32_bf16(aql[0], kh0, c, 0, 0, 0);
      c = __builtin_amdgcn_mfma_f32_16x16x32_bf16(aql[1], kh1, c, 0, 0, 0);
      st[nt] = c;
    }
    // online softmax (rows: q = (l>>4)*4+r, cols: nt*16 + (l&15))
    float mnew[4], alpha[4];
    #pragma unroll
    for (int r = 0; r < 4; r++){
      float mx = -1e30f;
      #pragma unroll
      for (int nt = 0; nt < 4; nt++) mx = fmaxf(mx, st[nt][r] * 0.125f);
      #pragma unroll
      for (int m = 1; m < 16; m <<= 1) mx = fmaxf(mx, __shfl_xor(mx, m));
      mnew[r] = fmaxf(mrun[r], mx);
      alpha[r] = __expf(mrun[r] - mnew[r]);
      mrun[r] = mnew[r];
    }
    float pv[4][4];
    #pragma unroll
    for (int r = 0; r < 4; r++){
      float srow = 0.f;
      #pragma unroll
      for (int nt = 0; nt < 4; nt++){
        float v = __expf(st[nt][r] * 0.125f - mnew[r]);
        pv[nt][r] = v; srow += v;
      }
      #pragma unroll
      for (int m = 1; m < 16; m <<= 1) srow += __shfl_xor(srow, m);
      lrun[r] = lrun[r] * alpha[r] + srow;
    }
    #pragma unroll
    for (int nt = 0; nt < 4; nt++)
      #pragma unroll
      for (int r = 0; r < 4; r++){
        BfPair p = split_bf(pv[nt][r]);
        int pidx = w * 1024 + ((l >> 4) * 4 + r) * 64 + nt * 16 + (l & 15);
        Ph[pidx] = p.hi;
        Pl[pidx] = p.lo;
      }
    asm volatile("s_waitcnt lgkmcnt(0)" ::: "memory");
    __builtin_amdgcn_sched_barrier(0);
    #pragma unroll
    for (int t4 = 0; t4 < 4; t4++)
      #pragma unroll
      for (int r = 0; r < 4; r++) oacc[t4][r] *= alpha[r];
    int paidx = w * 1024 + (l & 15) * 64 + 8 * (l >> 4);
    bf16x8 aph0 = *(const bf16x8*)&Ph[paidx];
    bf16x8 aph1 = *(const bf16x8*)&Ph[paidx + 32];
    bf16x8 apl0 = *(const bf16x8*)&Pl[paidx];
    bf16x8 apl1 = *(const bf16x8*)&Pl[paidx + 32];
    #pragma unroll
    for (int dt = 0; dt < 4; dt++){
      int vidx = (dt * 16 + (l & 15)) * 64 + 8 * (l >> 4);
      bf16x8 bvh0 = *(const bf16x8*)&Vsh[vidx];
      bf16x8 bvh1 = *(const bf16x8*)&Vsh[vidx + 32];
      bf16x8 bvl0 = *(const bf16x8*)&Vsl[vidx];
      bf16x8 bvl1 = *(const bf16x8*)&Vsl[vidx + 32];
      oacc[dt] = __builtin_amdgcn_mfma_f32_16x16x32_bf16(aph0, bvh0, oacc[dt], 0, 0, 0);
      oacc[dt] = __builtin_amdgcn_mfma_f32_16x16x32_bf16(aph1, bvh1, oacc[dt], 0, 0, 0);
      oacc[dt] = __builtin_amdgcn_mfma_f32_16x16x32_bf16(aph0, bvl0, oacc[dt], 0, 0, 0);
      oacc[dt] = __builtin_amdgcn_mfma_f32_16x16x32_bf16(aph1, bvl1, oacc[dt], 0, 0, 0);
      oacc[dt] = __builtin_amdgcn_mfma_f32_16x16x32_bf16(apl0, bvh0, oacc[dt], 0, 0, 0);
      oacc[dt] = __builtin_amdgcn_mfma_f32_16x16x32_bf16(apl1, bvh1, oacc[dt], 0, 0, 0);
    }
  }
  #pragma unroll
  for (int dt = 0; dt < 4; dt++)
    #pragma unroll
    for (int r = 0; r < 4; r++){
      int q = q0 + (l >> 4) * 4 + r;
      int col = h * DH_ + dt * 16 + (l & 15);
      float v = oacc[dt][r] / lrun[r];
      BfPair p = split_bf(v);
      oh[(size_t)(b * S_ + q) * D_ + col] = p.hi;
      ol[(size_t)(b * S_ + q) * D_ + col] = p.lo;
    }
}

// ---------------- router (f32) ----------------
__global__ __launch_bounds__(256) void k_router(
    const float* __restrict__ h2f, const float* __restrict__ Wg, const float* __restrict__ bg,
    const float* __restrict__ We, const float* __restrict__ be,
    int* __restrict__ flat, float* __restrict__ pc, int* __restrict__ moeI){
  int w = threadIdx.x >> 6, l = threadIdx.x & 63;
  int n = blockIdx.x * 4 + w;
  const float* hr = h2f + (size_t)n * D_;
  float pl[4] = {0.f, 0.f, 0.f, 0.f};
  for (int d = l; d < D_; d += 64){
    float hv = hr[d];
    float4 wg = *(const float4*)&Wg[d * 4];
    pl[0] += hv * wg.x; pl[1] += hv * wg.y; pl[2] += hv * wg.z; pl[3] += hv * wg.w;
  }
  #pragma unroll
  for (int m = 1; m < 64; m <<= 1)
    #pragma unroll
    for (int g = 0; g < 4; g++) pl[g] += __shfl_xor(pl[g], m);
  float lg[4];
  #pragma unroll
  for (int g = 0; g < 4; g++) lg[g] = pl[g] + bg[g];
  int gi = 0; float gm = lg[0];
  #pragma unroll
  for (int g = 1; g < 4; g++) if (lg[g] > gm){ gm = lg[g]; gi = g; }
  float gs = 0.f;
  #pragma unroll
  for (int g = 0; g < 4; g++) gs += expf(lg[g] - gm);
  float pg = 1.f / gs;
  float e0 = 0.f, e1 = 0.f;
  for (int d = l; d < D_; d += 64){
    float hv = hr[d];
    float2 we = *(const float2*)&We[((size_t)gi * D_ + d) * 2];
    e0 += hv * we.x; e1 += hv * we.y;
  }
  #pragma unroll
  for (int m = 1; m < 64; m <<= 1){ e0 += __shfl_xor(e0, m); e1 += __shfl_xor(e1, m); }
  e0 += be[gi * 2]; e1 += be[gi * 2 + 1];
  int ei; float pe;
  if (e1 > e0){ ei = 1; pe = 1.f / (1.f + expf(e0 - e1)); }
  else        { ei = 0; pe = 1.f / (1.f + expf(e1 - e0)); }
  if (l == 0){
    int f = gi * 2 + ei;
    flat[n] = f;
    pc[n] = pg * pe;
    atomicAdd(&moeI[f], 1);
  }
}

__global__ void k_init(int* moeI){ if (threadIdx.x < 16) moeI[threadIdx.x] = 0; }
__global__ void k_scan(int* moeI){
  if (threadIdx.x == 0){
    int s = 0;
    for (int e = 0; e < E_; e++){ moeI[16 + e] = s; s += moeI[e]; }
  }
}
__global__ void k_place(const int* __restrict__ flat, int* __restrict__ moeI, int* __restrict__ order){
  int n = blockIdx.x * 256 + threadIdx.x;
  if (n < NTOK){
    int f = flat[n];
    int pos = atomicAdd(&moeI[8 + f], 1);
    order[moeI[16 + f] + pos] = n;
  }
}

// ---------------- grouped GEMM 1: hid = gelu(h2 @ W1t^T + b1) ----------
__global__ __launch_bounds__(256) void k_moe_gemm1(
    const u16* __restrict__ h2, const u16* __restrict__ W1t, const float* __restrict__ b1,
    const int* __restrict__ order, const int* __restrict__ moeI, u16* __restrict__ hid){
  int e = blockIdx.z;
  int cnt = moeI[e];
  int mt = blockIdx.x;
  if (mt * 128 >= cnt) return;
  int off = moeI[16 + e];
  __shared__ alignas(16) u16 As[128 * 32];
  __shared__ alignas(16) u16 Bs[128 * 32];
  int tid = threadIdx.x, w = tid >> 6, l = tid & 63;
  int wr = w >> 1, wc = w & 1;
  int n0 = blockIdx.y * 128;
  f32x4 acc[4][4];
  #pragma unroll
  for (int i = 0; i < 4; i++)
    #pragma unroll
    for (int j = 0; j < 4; j++) acc[i][j] = f32x4{0.f, 0.f, 0.f, 0.f};
  int sr = w * 32 + (l >> 2);
  int kch = (l & 3) * 8;
  int tok0 = order[off + min(mt * 128 + sr, cnt - 1)];
  int tok1 = order[off + min(mt * 128 + sr + 16, cnt - 1)];
  const u16* Ag0 = h2 + (size_t)tok0 * D_ + kch;
  const u16* Ag1 = h2 + (size_t)tok1 * D_ + kch;
  const u16* Bt = W1t + (size_t)e * HID_ * D_;
  const u16* Bg0 = Bt + (size_t)(n0 + sr) * D_ + kch;
  const u16* Bg1 = Bg0 + (size_t)16 * D_;
  u16* AsB0 = &As[(w * 32) * 32];  u16* AsB1 = &As[(w * 32 + 16) * 32];
  u16* BsB0 = &Bs[(w * 32) * 32];  u16* BsB1 = &Bs[(w * 32 + 16) * 32];
  for (int k0 = 0; k0 < D_; k0 += 32){
    __syncthreads();
    gload_lds16(Ag0 + k0, AsB0);
    gload_lds16(Ag1 + k0, AsB1);
    gload_lds16(Bg0 + k0, BsB0);
    gload_lds16(Bg1 + k0, BsB1);
    __syncthreads();
    bf16x8 af[4], bfr[4];
    #pragma unroll
    for (int mi = 0; mi < 4; mi++) af[mi] = *(const bf16x8*)&As[(wr * 64 + mi * 16 + (l & 15)) * 32 + 8 * (l >> 4)];
    #pragma unroll
    for (int ni = 0; ni < 4; ni++) bfr[ni] = *(const bf16x8*)&Bs[(wc * 64 + ni * 16 + (l & 15)) * 32 + 8 * (l >> 4)];
    #pragma unroll
    for (int mi = 0; mi < 4; mi++)
      #pragma unroll
      for (int ni = 0; ni < 4; ni++)
        acc[mi][ni] = __builtin_amdgcn_mfma_f32_16x16x32_bf16(af[mi], bfr[ni], acc[mi][ni], 0, 0, 0);
  }
  int r4 = (l >> 4) * 4, cc = l & 15;
  #pragma unroll
  for (int mi = 0; mi < 4; mi++){
    #pragma unroll
    for (int ni = 0; ni < 4; ni++){
      int col = n0 + wc * 64 + ni * 16 + cc;
      float bv = b1[e * HID_ + col];
      #pragma unroll
      for (int r = 0; r < 4; r++){
        int rowl = wr * 64 + mi * 16 + r4 + r;
        if (mt * 128 + rowl < cnt){
          float v = gelu_tanh(acc[mi][ni][r] + bv);
          hid[(size_t)(off + mt * 128 + rowl) * HID_ + col] = f2bf(v);
        }
      }
    }
  }
}

// ---------------- grouped GEMM 2: out = x2 + p*(hid @ W2t^T + b2) ----
__global__ __launch_bounds__(256) void k_moe_gemm2(
    const u16* __restrict__ hid, const u16* __restrict__ W2t, const float* __restrict__ b2,
    const int* __restrict__ order, const int* __restrict__ moeI,
    const float* __restrict__ pc, const float* __restrict__ x2, float* __restrict__ out){
  int e = blockIdx.z;
  int cnt = moeI[e];
  int mt = blockIdx.x;
  if (mt * 128 >= cnt) return;
  int off = moeI[16 + e];
  __shared__ alignas(16) u16 As[128 * 32];
  __shared__ alignas(16) u16 Bs[128 * 32];
  int tid = threadIdx.x, w = tid >> 6, l = tid & 63;
  int wr = w >> 1, wc = w & 1;
  int n0 = blockIdx.y * 128;
  f32x4 acc[4][4];
  #pragma unroll
  for (int i = 0; i < 4; i++)
    #pragma unroll
    for (int j = 0; j < 4; j++) acc[i][j] = f32x4{0.f, 0.f, 0.f, 0.f};
  int sr = w * 32 + (l >> 2);
  int kch = (l & 3) * 8;
  int ar0 = off + min(mt * 128 + sr, cnt - 1);
  int ar1 = off + min(mt * 128 + sr + 16, cnt - 1);
  const u16* Ag0 = hid + (size_t)ar0 * HID_ + kch;
  const u16* Ag1 = hid + (size_t)ar1 * HID_ + kch;
  const u16* Bt = W2t + (size_t)e * D_ * HID_;
  const u16* Bg0 = Bt + (size_t)(n0 + sr) * HID_ + kch;
  const u16* Bg1 = Bg0 + (size_t)16 * HID_;
  u16* AsB0 = &As[(w * 32) * 32];  u16* AsB1 = &As[(w * 32 + 16) * 32];
  u16* BsB0 = &Bs[(w * 32) * 32];  u16* BsB1 = &Bs[(w * 32 + 16) * 32];
  for (int k0 = 0; k0 < HID_; k0 += 32){
    __syncthreads();
    gload_lds16(Ag0 + k0, AsB0);
    gload_lds16(Ag1 + k0, AsB1);
    gload_lds16(Bg0 + k0, BsB0);
    gload_lds16(Bg1 + k0, BsB1);
    __syncthreads();
    bf16x8 af[4], bfr[4];
    #pragma unroll
    for (int mi = 0; mi < 4; mi++) af[mi] = *(const bf16x8*)&As[(wr * 64 + mi * 16 + (l & 15)) * 32 + 8 * (l >> 4)];
    #pragma unroll
    for (int ni = 0; ni < 4; ni++) bfr[ni] = *(const bf16x8*)&Bs[(wc * 64 + ni * 16 + (l & 15)) * 32 + 8 * (l >> 4)];
    #pragma unroll
    for (int mi = 0; mi < 4; mi++)
      #pragma unroll
      for (int ni = 0; ni < 4; ni++)
        acc[mi][ni] = __builtin_amdgcn_mfma_f32_16x16x32_bf16(af[mi], bfr[ni], acc[mi][ni], 0, 0, 0);
  }
  int r4 = (l >> 4) * 4, cc = l & 15;
  #pragma unroll
  for (int mi = 0; mi < 4; mi++){
    #pragma unroll
    for (int r = 0; r < 4; r++){
      int rowl = wr * 64 + mi * 16 + r4 + r;
      if (mt * 128 + rowl < cnt){
        int tok = order[off + mt * 128 + rowl];
        float pv = pc[tok];
        #pragma unroll
        for (int ni = 0; ni < 4; ni++){
          int col = n0 + wc * 64 + ni * 16 + cc;
          float v = acc[mi][ni][r] + b2[e * D_ + col];
          out[(size_t)tok * D_ + col] = x2[(size_t)tok * D_ + col] + pv * v;
        }
      }
    }
  }
}

extern "C" void kernel_launch(void* const* d_in, const int* in_sizes, int n_in,
                              void* d_out, int out_size, void* d_ws, size_t ws_size,
                              hipStream_t stream){
  const float* x         = (const float*)d_in[0];
  const float* ln1_w     = (const float*)d_in[1];
  const float* ln1_b     = (const float*)d_in[2];
  const float* in_proj_w = (const float*)d_in[3];
  const float* in_proj_b = (const float*)d_in[4];
  const float* out_proj_w= (const float*)d_in[5];
  const float* out_proj_b= (const float*)d_in[6];
  const float* ln2_w     = (const float*)d_in[7];
  const float* ln2_b     = (const float*)d_in[8];
  const float* Wg        = (const float*)d_in[9];
  const float* bg        = (const float*)d_in[10];
  const float* We        = (const float*)d_in[11];
  const float* be        = (const float*)d_in[12];
  const float* W1        = (const float*)d_in[13];
  const float* b1        = (const float*)d_in[14];
  const float* W2        = (const float*)d_in[15];
  const float* b2        = (const float*)d_in[16];
  float* out = (float*)d_out;

  char* ws = (char*)d_ws;
  size_t off = 0;
  auto alloc = [&](size_t bytes) -> char* {
    char* p = ws + off;
    off += (bytes + 255) & ~(size_t)255;
    return p;
  };
  u16*   inpTh = (u16*)  alloc((size_t)3 * D_ * D_ * 2);
  u16*   inpTl = (u16*)  alloc((size_t)3 * D_ * D_ * 2);
  u16*   outpTh= (u16*)  alloc((size_t)D_ * D_ * 2);
  u16*   outpTl= (u16*)  alloc((size_t)D_ * D_ * 2);
  u16*   W1t  = (u16*)  alloc((size_t)E_ * HID_ * D_ * 2);
  u16*   W2t  = (u16*)  alloc((size_t)E_ * D_ * HID_ * 2);
  u16*   qkvh = (u16*)  alloc((size_t)NTOK * 3 * D_ * 2);
  u16*   qkvl = (u16*)  alloc((size_t)NTOK * 3 * D_ * 2);
  u16*   h1h  = (u16*)  alloc((size_t)NTOK * D_ * 2);
  u16*   h1l  = (u16*)  alloc((size_t)NTOK * D_ * 2);
  u16*   vth  = (u16*)  alloc((size_t)B_ * NH_ * DH_ * S_ * 2);
  u16*   vtl  = (u16*)  alloc((size_t)B_ * NH_ * DH_ * S_ * 2);
  float* x2   = (float*)alloc((size_t)NTOK * D_ * 4);
  u16*   h2   = (u16*)  alloc((size_t)NTOK * D_ * 2);
  int*   flat = (int*)  alloc(NTOK * 4);
  float* pc   = (float*)alloc(NTOK * 4);
  int*   order= (int*)  alloc(NTOK * 4);
  int*   moeI = (int*)  alloc(32 * 4);
  // aliases (lifetimes disjoint):
  float* h2f  = (float*)qkvh;   // written by LN2 after qkv is dead
  u16*   hid  = (u16*)qkvl;     // written by moe_gemm1 after qkv is dead
  u16*   attnh= h1h;            // h1 dead after QKV GEMM
  u16*   attnl= h1l;

  // weight prep
  k_convert_split<<<dim3((3 * D_ * D_ / 4 + 255) / 256), dim3(256), 0, stream>>>(in_proj_w, inpTh, inpTl, 3 * D_ * D_ / 4);
  k_convert_split<<<dim3((D_ * D_ / 4 + 255) / 256), dim3(256), 0, stream>>>(out_proj_w, outpTh, outpTl, D_ * D_ / 4);
  k_transpose_bf16<<<dim3(HID_ / 32, D_ / 32, E_), dim3(32, 8), 0, stream>>>(W1, W1t, D_, HID_);
  k_transpose_bf16<<<dim3(D_ / 32, HID_ / 32, E_), dim3(32, 8), 0, stream>>>(W2, W2t, HID_, D_);

  // LN1 (split output)
  k_layernorm<<<dim3(NTOK), dim3(256), 0, stream>>>(x, ln1_w, ln1_b, h1h, h1l, (float*)nullptr);
  // QKV (split GEMM -> split output)
  k_gemm3<0><<<dim3(NTOK / 128, 3 * D_ / 128), dim3(256), 0, stream>>>(
      h1h, h1l, inpTh, inpTl, in_proj_b, nullptr, qkvh, qkvl, nullptr, NTOK, 3 * D_, D_);
  // V transpose
  k_transpose_v<<<dim3(DH_ / 32, S_ / 32, B_ * NH_), dim3(32, 8), 0, stream>>>(qkvh, qkvl, vth, vtl);
  // attention (split)
  k_attn3<<<dim3(S_ / 64, B_ * NH_), dim3(256), 0, stream>>>(qkvh, qkvl, vth, vtl, attnh, attnl);
  // out-proj + residual -> x2 (f32)
  k_gemm3<1><<<dim3(NTOK / 128, D_ / 128), dim3(256), 0, stream>>>(
      attnh, attnl, outpTh, outpTl, out_proj_b, x, nullptr, nullptr, x2, NTOK, D_, D_);
  // LN2: bf16 hi for MoE + f32 for router
  k_layernorm<<<dim3(NTOK), dim3(256), 0, stream>>>(x2, ln2_w, ln2_b, h2, (u16*)nullptr, h2f);
  // router + bucketing
  k_init<<<dim3(1), dim3(64), 0, stream>>>(moeI);
  k_router<<<dim3(NTOK / 4), dim3(256), 0, stream>>>(h2f, Wg, bg, We, be, flat, pc, moeI);
  k_scan<<<dim3(1), dim3(64), 0, stream>>>(moeI);
  k_place<<<dim3(NTOK / 256), dim3(256), 0, stream>>>(flat, moeI, order);
  // grouped expert GEMMs
  k_moe_gemm1<<<dim3(NTOK / 128, HID_ / 128, E_), dim3(256), 0, stream>>>(h2, W1t, b1, order, moeI, hid);
  k_moe_gemm2<<<dim3(NTOK / 128, D_ / 128, E_), dim3(256), 0, stream>>>(hid, W2t, b2, order, moeI, pc, x2, out);
}

// Round 4
// 296.563 us; speedup vs baseline: 1.1882x; 1.1882x over previous
//
#include <hip/hip_runtime.h>
#include <stdint.h>

#define B_ 2
#define S_ 1024
#define D_ 768
#define NH_ 12
#define DH_ 64
#define HID_ 1536
#define G_ 4
#define EPG_ 2
#define E_ 8
#define NTOK (B_*S_)

typedef unsigned short u16;
typedef __bf16 bf16x8 __attribute__((ext_vector_type(8)));
typedef float f32x4 __attribute__((ext_vector_type(4)));
typedef u16 u16x4 __attribute__((ext_vector_type(4)));
typedef u16 u16x8 __attribute__((ext_vector_type(8)));

struct BfPair { u16 hi, lo; };

__device__ __forceinline__ u16 f2bf(float f){
  unsigned u = __builtin_bit_cast(unsigned, f);
  u += 0x7FFFu + ((u >> 16) & 1u);
  return (u16)(u >> 16);
}
__device__ __forceinline__ float bf2f(u16 h){
  unsigned u = ((unsigned)h) << 16;
  return __builtin_bit_cast(float, u);
}
__device__ __forceinline__ BfPair split_bf(float v){
  BfPair p;
  p.hi = f2bf(v);
  p.lo = f2bf(v - bf2f(p.hi));
  return p;
}
__device__ __forceinline__ float gelu_tanh(float x){
  float t = 0.7978845608028654f * (x + 0.044715f * x * x * x);
  float e = __expf(2.f * t);
  float th = 1.f - 2.f / (e + 1.f);
  return 0.5f * x * (1.f + th);
}
__device__ __forceinline__ void gload_lds16(const void* g, void* l){
  __builtin_amdgcn_global_load_lds(
      (const __attribute__((address_space(1))) void*)g,
      (__attribute__((address_space(3))) void*)l, 16, 0, 0);
}

// ---------------- convert+split f32 -> (bf16 hi, bf16 lo) ----------------
__global__ void k_convert_split(const float* __restrict__ src, u16* __restrict__ dh,
                                u16* __restrict__ dl, int n4){
  int i = blockIdx.x * blockDim.x + threadIdx.x;
  if (i < n4){
    float4 v = ((const float4*)src)[i];
    u16x4 oh, ol;
    BfPair p0 = split_bf(v.x), p1 = split_bf(v.y), p2 = split_bf(v.z), p3 = split_bf(v.w);
    oh.x = p0.hi; ol.x = p0.lo;
    oh.y = p1.hi; ol.y = p1.lo;
    oh.z = p2.hi; ol.z = p2.lo;
    oh.w = p3.hi; ol.w = p3.lo;
    ((u16x4*)dh)[i] = oh;
    ((u16x4*)dl)[i] = ol;
  }
}

// ---------------- tiled transpose + convert: src [E][R][C] f32 -> dst [E][C][R] bf16 ----
__global__ void k_transpose_bf16(const float* __restrict__ src, u16* __restrict__ dst, int R, int C){
  __shared__ float tile[32][33];
  int e = blockIdx.z;
  const float* s = src + (size_t)e * R * C;
  u16* d = dst + (size_t)e * R * C;
  int c0 = blockIdx.x * 32, r0 = blockIdx.y * 32;
  #pragma unroll
  for (int i = 0; i < 32; i += 8)
    tile[threadIdx.y + i][threadIdx.x] = s[(size_t)(r0 + threadIdx.y + i) * C + c0 + threadIdx.x];
  __syncthreads();
  #pragma unroll
  for (int i = 0; i < 32; i += 8)
    d[(size_t)(c0 + threadIdx.y + i) * R + r0 + threadIdx.x] = f2bf(tile[threadIdx.x][threadIdx.y + i]);
}

// ---------------- V transpose: qkv hi/lo [N][2304] -> vt hi/lo [BH][64][1024] ----------
__global__ void k_transpose_v(const u16* __restrict__ qh, const u16* __restrict__ ql,
                              u16* __restrict__ vth, u16* __restrict__ vtl){
  __shared__ u16 th[32][34], tl[32][34];
  int bh = blockIdx.z, b = bh / NH_, h = bh % NH_;
  int d0 = blockIdx.x * 32, s0 = blockIdx.y * 32;
  #pragma unroll
  for (int i = 0; i < 32; i += 8){
    size_t src = (size_t)(b * S_ + s0 + threadIdx.y + i) * (3 * D_) + 2 * D_ + h * DH_ + d0 + threadIdx.x;
    th[threadIdx.y + i][threadIdx.x] = qh[src];
    tl[threadIdx.y + i][threadIdx.x] = ql[src];
  }
  __syncthreads();
  #pragma unroll
  for (int i = 0; i < 32; i += 8){
    size_t dst = ((size_t)bh * DH_ + d0 + threadIdx.y + i) * S_ + s0 + threadIdx.x;
    vth[dst] = th[threadIdx.x][threadIdx.y + i];
    vtl[dst] = tl[threadIdx.x][threadIdx.y + i];
  }
}

// ---------------- layernorm: f32 in -> bf16 hi (+lo) (+f32) ----------------
__global__ __launch_bounds__(256) void k_layernorm(
    const float* __restrict__ x, const float* __restrict__ w, const float* __restrict__ b,
    u16* __restrict__ oh, u16* __restrict__ ol, float* __restrict__ of){
  int row = blockIdx.x;
  const float* xr = x + (size_t)row * D_;
  int t = threadIdx.x;
  float v0 = xr[t], v1 = xr[t + 256], v2 = xr[t + 512];
  float s = v0 + v1 + v2;
  float sq = v0 * v0 + v1 * v1 + v2 * v2;
  #pragma unroll
  for (int m = 1; m < 64; m <<= 1){ s += __shfl_xor(s, m); sq += __shfl_xor(sq, m); }
  __shared__ float ls[4], lq[4];
  int wid = t >> 6;
  if ((t & 63) == 0){ ls[wid] = s; lq[wid] = sq; }
  __syncthreads();
  s = ls[0] + ls[1] + ls[2] + ls[3];
  sq = lq[0] + lq[1] + lq[2] + lq[3];
  float mean = s * (1.f / D_);
  float var = sq * (1.f / D_) - mean * mean;
  float rstd = rsqrtf(var + 1e-5f);
  #pragma unroll
  for (int i = 0; i < 3; i++){
    int dcol = t + i * 256;
    float v = (i == 0 ? v0 : (i == 1 ? v1 : v2));
    float y = (v - mean) * rstd * w[dcol] + b[dcol];
    BfPair p = split_bf(y);
    oh[(size_t)row * D_ + dcol] = p.hi;
    if (ol) ol[(size_t)row * D_ + dcol] = p.lo;
    if (of) of[(size_t)row * D_ + dcol] = y;
  }
}

// ------- pipelined split-precision GEMM 64x64: C = (Ah+Al)(Bh+Bl)^T + bias -------
// EPI 0: store split bf16. EPI 1: store f32 + resid.
template<int EPI>
__global__ __launch_bounds__(256) void k_gemm3(
    const u16* __restrict__ Ah, const u16* __restrict__ Al,
    const u16* __restrict__ Bh, const u16* __restrict__ Bl,
    const float* __restrict__ bias, const float* __restrict__ resid,
    u16* __restrict__ outh, u16* __restrict__ outl, float* __restrict__ outf,
    int M, int N, int K){
  __shared__ alignas(16) u16 Ash[2][64 * 32];
  __shared__ alignas(16) u16 Asl[2][64 * 32];
  __shared__ alignas(16) u16 Bsh[2][64 * 32];
  __shared__ alignas(16) u16 Bsl[2][64 * 32];
  int m0 = blockIdx.x * 64, n0 = blockIdx.y * 64;
  int tid = threadIdx.x, w = tid >> 6, l = tid & 63;
  int wr = w >> 1, wc = w & 1;
  f32x4 acc[2][2];
  #pragma unroll
  for (int i = 0; i < 2; i++)
    #pragma unroll
    for (int j = 0; j < 2; j++) acc[i][j] = f32x4{0.f, 0.f, 0.f, 0.f};
  int srow = w * 16 + (l >> 2);
  int scol = (l & 3) * 8;
  const u16* gAh = Ah + (size_t)(m0 + srow) * K + scol;
  const u16* gAl = Al + (size_t)(m0 + srow) * K + scol;
  const u16* gBh = Bh + (size_t)(n0 + srow) * K + scol;
  const u16* gBl = Bl + (size_t)(n0 + srow) * K + scol;
  int dOff = (w * 16) * 32;  // wave-uniform LDS dst
  auto STAGE = [&](int buf, int k0){
    gload_lds16(gAh + k0, &Ash[buf][dOff]);
    gload_lds16(gAl + k0, &Asl[buf][dOff]);
    gload_lds16(gBh + k0, &Bsh[buf][dOff]);
    gload_lds16(gBl + k0, &Bsl[buf][dOff]);
  };
  STAGE(0, 0);
  __syncthreads();
  int nk = K / 32;
  int ai = (wr * 32 + (l & 15)) * 32 + 8 * (l >> 4);
  int bi = (wc * 32 + (l & 15)) * 32 + 8 * (l >> 4);
  for (int t = 0; t < nk; t++){
    int cur = t & 1;
    if (t + 1 < nk) STAGE(cur ^ 1, (t + 1) * 32);
    bf16x8 afh[2], afl[2], bfh[2], bfl[2];
    #pragma unroll
    for (int mi = 0; mi < 2; mi++){
      afh[mi] = *(const bf16x8*)&Ash[cur][ai + mi * 16 * 32];
      afl[mi] = *(const bf16x8*)&Asl[cur][ai + mi * 16 * 32];
    }
    #pragma unroll
    for (int ni = 0; ni < 2; ni++){
      bfh[ni] = *(const bf16x8*)&Bsh[cur][bi + ni * 16 * 32];
      bfl[ni] = *(const bf16x8*)&Bsl[cur][bi + ni * 16 * 32];
    }
    #pragma unroll
    for (int mi = 0; mi < 2; mi++)
      #pragma unroll
      for (int ni = 0; ni < 2; ni++){
        acc[mi][ni] = __builtin_amdgcn_mfma_f32_16x16x32_bf16(afh[mi], bfh[ni], acc[mi][ni], 0, 0, 0);
        acc[mi][ni] = __builtin_amdgcn_mfma_f32_16x16x32_bf16(afh[mi], bfl[ni], acc[mi][ni], 0, 0, 0);
        acc[mi][ni] = __builtin_amdgcn_mfma_f32_16x16x32_bf16(afl[mi], bfh[ni], acc[mi][ni], 0, 0, 0);
      }
    __syncthreads();
  }
  int r4 = (l >> 4) * 4, cc = l & 15;
  #pragma unroll
  for (int mi = 0; mi < 2; mi++){
    #pragma unroll
    for (int ni = 0; ni < 2; ni++){
      int col = n0 + wc * 32 + ni * 16 + cc;
      float bv = bias ? bias[col] : 0.f;
      #pragma unroll
      for (int r = 0; r < 4; r++){
        int row = m0 + wr * 32 + mi * 16 + r4 + r;
        float v = acc[mi][ni][r] + bv;
        if (EPI == 0){
          BfPair p = split_bf(v);
          outh[(size_t)row * N + col] = p.hi;
          outl[(size_t)row * N + col] = p.lo;
        } else {
          outf[(size_t)row * N + col] = v + resid[(size_t)row * N + col];
        }
      }
    }
  }
}

// ---------------- split-precision flash attention (K/V double-buffered) ----------------
__global__ __launch_bounds__(256) void k_attn3(
    const u16* __restrict__ qkvh, const u16* __restrict__ qkvl,
    const u16* __restrict__ vth, const u16* __restrict__ vtl,
    u16* __restrict__ oh, u16* __restrict__ ol){
  __shared__ alignas(16) u16 Ksh[2][64 * 64];
  __shared__ alignas(16) u16 Ksl[2][64 * 64];
  __shared__ alignas(16) u16 Vsh[2][64 * 64];
  __shared__ alignas(16) u16 Vsl[2][64 * 64];
  __shared__ alignas(16) u16 Ph[4 * 16 * 64];
  __shared__ alignas(16) u16 Pl[4 * 16 * 64];
  int bh = blockIdx.y;
  int b = bh / NH_, h = bh % NH_;
  int qb = blockIdx.x;
  int tid = threadIdx.x, w = tid >> 6, l = tid & 63;
  int q0 = qb * 64 + w * 16;
  const int RS = 3 * D_;
  size_t qoff = (size_t)(b * S_ + q0 + (l & 15)) * RS + h * DH_ + 8 * (l >> 4);
  bf16x8 aqh[2], aql[2];
  aqh[0] = *(const bf16x8*)(qkvh + qoff); aqh[1] = *(const bf16x8*)(qkvh + qoff + 32);
  aql[0] = *(const bf16x8*)(qkvl + qoff); aql[1] = *(const bf16x8*)(qkvl + qoff + 32);
  f32x4 oacc[4];
  #pragma unroll
  for (int i = 0; i < 4; i++) oacc[i] = f32x4{0.f, 0.f, 0.f, 0.f};
  float mrun[4], lrun[4];
  #pragma unroll
  for (int r = 0; r < 4; r++){ mrun[r] = -1e30f; lrun[r] = 0.f; }

  size_t koff = (size_t)(b * S_ + w * 16 + (l >> 3)) * RS + D_ + h * DH_ + (l & 7) * 8;
  const u16* Kgh = qkvh + koff;
  const u16* Kgl = qkvl + koff;
  size_t voff = ((size_t)bh * DH_ + w * 16 + (l >> 3)) * S_ + (l & 7) * 8;
  const u16* Vgh = vth + voff;
  const u16* Vgl = vtl + voff;
  int kb0 = (w * 16) * 64;       // wave-uniform dst (rows w*16..)
  int kb1 = (w * 16 + 8) * 64;

  auto STAGE = [&](int buf, int kt){
    gload_lds16(Kgh + (size_t)(kt * 64) * RS, &Ksh[buf][kb0]);
    gload_lds16(Kgh + (size_t)(kt * 64 + 8) * RS, &Ksh[buf][kb1]);
    gload_lds16(Kgl + (size_t)(kt * 64) * RS, &Ksl[buf][kb0]);
    gload_lds16(Kgl + (size_t)(kt * 64 + 8) * RS, &Ksl[buf][kb1]);
    gload_lds16(Vgh + kt * 64, &Vsh[buf][kb0]);
    gload_lds16(Vgh + kt * 64 + 8 * S_, &Vsh[buf][kb1]);
    gload_lds16(Vgl + kt * 64, &Vsl[buf][kb0]);
    gload_lds16(Vgl + kt * 64 + 8 * S_, &Vsl[buf][kb1]);
  };
  STAGE(0, 0);
  __syncthreads();

  for (int kt = 0; kt < S_ / 64; kt++){
    int cur = kt & 1;
    if (kt + 1 < S_ / 64) STAGE(cur ^ 1, kt + 1);
    // QK^T (3-term split)
    f32x4 st[4];
    #pragma unroll
    for (int nt = 0; nt < 4; nt++){
      int idx = (nt * 16 + (l & 15)) * 64 + 8 * (l >> 4);
      bf16x8 kh0 = *(const bf16x8*)&Ksh[cur][idx];
      bf16x8 kh1 = *(const bf16x8*)&Ksh[cur][idx + 32];
      bf16x8 kl0 = *(const bf16x8*)&Ksl[cur][idx];
      bf16x8 kl1 = *(const bf16x8*)&Ksl[cur][idx + 32];
      f32x4 c = f32x4{0.f, 0.f, 0.f, 0.f};
      c = __builtin_amdgcn_mfma_f32_16x16x32_bf16(aqh[0], kh0, c, 0, 0, 0);
      c = __builtin_amdgcn_mfma_f32_16x16x32_bf16(aqh[1], kh1, c, 0, 0, 0);
      c = __builtin_amdgcn_mfma_f32_16x16x32_bf16(aqh[0], kl0, c, 0, 0, 0);
      c = __builtin_amdgcn_mfma_f32_16x16x32_bf16(aqh[1], kl1, c, 0, 0, 0);
      c = __builtin_amdgcn_mfma_f32_16x16x32_bf16(aql[0], kh0, c, 0, 0, 0);
      c = __builtin_amdgcn_mfma_f32_16x16x32_bf16(aql[1], kh1, c, 0, 0, 0);
      st[nt] = c;
    }
    // online softmax (rows: q = (l>>4)*4+r, cols: nt*16 + (l&15))
    float mnew[4], alpha[4];
    #pragma unroll
    for (int r = 0; r < 4; r++){
      float mx = -1e30f;
      #pragma unroll
      for (int nt = 0; nt < 4; nt++) mx = fmaxf(mx, st[nt][r] * 0.125f);
      #pragma unroll
      for (int m = 1; m < 16; m <<= 1) mx = fmaxf(mx, __shfl_xor(mx, m));
      mnew[r] = fmaxf(mrun[r], mx);
      alpha[r] = __expf(mrun[r] - mnew[r]);
      mrun[r] = mnew[r];
    }
    float pv[4][4];
    #pragma unroll
    for (int r = 0; r < 4; r++){
      float srow = 0.f;
      #pragma unroll
      for (int nt = 0; nt < 4; nt++){
        float v = __expf(st[nt][r] * 0.125f - mnew[r]);
        pv[nt][r] = v; srow += v;
      }
      #pragma unroll
      for (int m = 1; m < 16; m <<= 1) srow += __shfl_xor(srow, m);
      lrun[r] = lrun[r] * alpha[r] + srow;
    }
    #pragma unroll
    for (int nt = 0; nt < 4; nt++)
      #pragma unroll
      for (int r = 0; r < 4; r++){
        BfPair p = split_bf(pv[nt][r]);
        int pidx = w * 1024 + ((l >> 4) * 4 + r) * 64 + nt * 16 + (l & 15);
        Ph[pidx] = p.hi;
        Pl[pidx] = p.lo;
      }
    asm volatile("s_waitcnt lgkmcnt(0)" ::: "memory");
    __builtin_amdgcn_sched_barrier(0);
    #pragma unroll
    for (int t4 = 0; t4 < 4; t4++)
      #pragma unroll
      for (int r = 0; r < 4; r++) oacc[t4][r] *= alpha[r];
    int paidx = w * 1024 + (l & 15) * 64 + 8 * (l >> 4);
    bf16x8 aph0 = *(const bf16x8*)&Ph[paidx];
    bf16x8 aph1 = *(const bf16x8*)&Ph[paidx + 32];
    bf16x8 apl0 = *(const bf16x8*)&Pl[paidx];
    bf16x8 apl1 = *(const bf16x8*)&Pl[paidx + 32];
    #pragma unroll
    for (int dt = 0; dt < 4; dt++){
      int vidx = (dt * 16 + (l & 15)) * 64 + 8 * (l >> 4);
      bf16x8 bvh0 = *(const bf16x8*)&Vsh[cur][vidx];
      bf16x8 bvh1 = *(const bf16x8*)&Vsh[cur][vidx + 32];
      bf16x8 bvl0 = *(const bf16x8*)&Vsl[cur][vidx];
      bf16x8 bvl1 = *(const bf16x8*)&Vsl[cur][vidx + 32];
      oacc[dt] = __builtin_amdgcn_mfma_f32_16x16x32_bf16(aph0, bvh0, oacc[dt], 0, 0, 0);
      oacc[dt] = __builtin_amdgcn_mfma_f32_16x16x32_bf16(aph1, bvh1, oacc[dt], 0, 0, 0);
      oacc[dt] = __builtin_amdgcn_mfma_f32_16x16x32_bf16(aph0, bvl0, oacc[dt], 0, 0, 0);
      oacc[dt] = __builtin_amdgcn_mfma_f32_16x16x32_bf16(aph1, bvl1, oacc[dt], 0, 0, 0);
      oacc[dt] = __builtin_amdgcn_mfma_f32_16x16x32_bf16(apl0, bvh0, oacc[dt], 0, 0, 0);
      oacc[dt] = __builtin_amdgcn_mfma_f32_16x16x32_bf16(apl1, bvh1, oacc[dt], 0, 0, 0);
    }
    __syncthreads();
  }
  #pragma unroll
  for (int dt = 0; dt < 4; dt++)
    #pragma unroll
    for (int r = 0; r < 4; r++){
      int q = q0 + (l >> 4) * 4 + r;
      int col = h * DH_ + dt * 16 + (l & 15);
      float v = oacc[dt][r] / lrun[r];
      BfPair p = split_bf(v);
      oh[(size_t)(b * S_ + q) * D_ + col] = p.hi;
      ol[(size_t)(b * S_ + q) * D_ + col] = p.lo;
    }
}

// ---------------- router (f32) ----------------
__global__ __launch_bounds__(256) void k_router(
    const float* __restrict__ h2f, const float* __restrict__ Wg, const float* __restrict__ bg,
    const float* __restrict__ We, const float* __restrict__ be,
    int* __restrict__ flat, float* __restrict__ pc, int* __restrict__ moeI){
  int w = threadIdx.x >> 6, l = threadIdx.x & 63;
  int n = blockIdx.x * 4 + w;
  const float* hr = h2f + (size_t)n * D_;
  float pl[4] = {0.f, 0.f, 0.f, 0.f};
  for (int d = l; d < D_; d += 64){
    float hv = hr[d];
    float4 wg = *(const float4*)&Wg[d * 4];
    pl[0] += hv * wg.x; pl[1] += hv * wg.y; pl[2] += hv * wg.z; pl[3] += hv * wg.w;
  }
  #pragma unroll
  for (int m = 1; m < 64; m <<= 1)
    #pragma unroll
    for (int g = 0; g < 4; g++) pl[g] += __shfl_xor(pl[g], m);
  float lg[4];
  #pragma unroll
  for (int g = 0; g < 4; g++) lg[g] = pl[g] + bg[g];
  int gi = 0; float gm = lg[0];
  #pragma unroll
  for (int g = 1; g < 4; g++) if (lg[g] > gm){ gm = lg[g]; gi = g; }
  float gs = 0.f;
  #pragma unroll
  for (int g = 0; g < 4; g++) gs += expf(lg[g] - gm);
  float pg = 1.f / gs;
  float e0 = 0.f, e1 = 0.f;
  for (int d = l; d < D_; d += 64){
    float hv = hr[d];
    float2 we = *(const float2*)&We[((size_t)gi * D_ + d) * 2];
    e0 += hv * we.x; e1 += hv * we.y;
  }
  #pragma unroll
  for (int m = 1; m < 64; m <<= 1){ e0 += __shfl_xor(e0, m); e1 += __shfl_xor(e1, m); }
  e0 += be[gi * 2]; e1 += be[gi * 2 + 1];
  int ei; float pe;
  if (e1 > e0){ ei = 1; pe = 1.f / (1.f + expf(e0 - e1)); }
  else        { ei = 0; pe = 1.f / (1.f + expf(e1 - e0)); }
  if (l == 0){
    int f = gi * 2 + ei;
    flat[n] = f;
    pc[n] = pg * pe;
    atomicAdd(&moeI[f], 1);
  }
}

__global__ void k_init(int* moeI){ if (threadIdx.x < 16) moeI[threadIdx.x] = 0; }
__global__ void k_scan(int* moeI){
  if (threadIdx.x == 0){
    int s = 0;
    for (int e = 0; e < E_; e++){ moeI[16 + e] = s; s += moeI[e]; }
  }
}
__global__ void k_place(const int* __restrict__ flat, int* __restrict__ moeI, int* __restrict__ order){
  int n = blockIdx.x * 256 + threadIdx.x;
  if (n < NTOK){
    int f = flat[n];
    int pos = atomicAdd(&moeI[8 + f], 1);
    order[moeI[16 + f] + pos] = n;
  }
}

// ------- pipelined grouped GEMM 1 (64x64): hid = gelu(h2 @ W1t^T + b1) -------
// grid (8, 32, HID/64): e = blockIdx.x -> XCD pinning
__global__ __launch_bounds__(256) void k_moe_gemm1(
    const u16* __restrict__ h2, const u16* __restrict__ W1t, const float* __restrict__ b1,
    const int* __restrict__ order, const int* __restrict__ moeI, u16* __restrict__ hid){
  int e = blockIdx.x, mt = blockIdx.y, nt = blockIdx.z;
  int cnt = moeI[e];
  if (mt * 64 >= cnt) return;
  int off = moeI[16 + e];
  __shared__ alignas(16) u16 As[2][64 * 32];
  __shared__ alignas(16) u16 Bs[2][64 * 32];
  int tid = threadIdx.x, w = tid >> 6, l = tid & 63;
  int wr = w >> 1, wc = w & 1;
  f32x4 acc[2][2];
  #pragma unroll
  for (int i = 0; i < 2; i++)
    #pragma unroll
    for (int j = 0; j < 2; j++) acc[i][j] = f32x4{0.f, 0.f, 0.f, 0.f};
  int srow = w * 16 + (l >> 2);
  int scol = (l & 3) * 8;
  int tok = order[off + min(mt * 64 + srow, cnt - 1)];
  const u16* gA = h2 + (size_t)tok * D_ + scol;
  const u16* gB = W1t + (size_t)e * HID_ * D_ + (size_t)(nt * 64 + srow) * D_ + scol;
  int dOff = (w * 16) * 32;
  auto STAGE = [&](int buf, int k0){
    gload_lds16(gA + k0, &As[buf][dOff]);
    gload_lds16(gB + k0, &Bs[buf][dOff]);
  };
  STAGE(0, 0);
  __syncthreads();
  int ai = (wr * 32 + (l & 15)) * 32 + 8 * (l >> 4);
  int bi = (wc * 32 + (l & 15)) * 32 + 8 * (l >> 4);
  const int nk = D_ / 32;
  for (int t = 0; t < nk; t++){
    int cur = t & 1;
    if (t + 1 < nk) STAGE(cur ^ 1, (t + 1) * 32);
    bf16x8 af[2], bfr[2];
    #pragma unroll
    for (int mi = 0; mi < 2; mi++) af[mi] = *(const bf16x8*)&As[cur][ai + mi * 16 * 32];
    #pragma unroll
    for (int ni = 0; ni < 2; ni++) bfr[ni] = *(const bf16x8*)&Bs[cur][bi + ni * 16 * 32];
    #pragma unroll
    for (int mi = 0; mi < 2; mi++)
      #pragma unroll
      for (int ni = 0; ni < 2; ni++)
        acc[mi][ni] = __builtin_amdgcn_mfma_f32_16x16x32_bf16(af[mi], bfr[ni], acc[mi][ni], 0, 0, 0);
    __syncthreads();
  }
  int r4 = (l >> 4) * 4, cc = l & 15;
  #pragma unroll
  for (int mi = 0; mi < 2; mi++){
    #pragma unroll
    for (int ni = 0; ni < 2; ni++){
      int col = nt * 64 + wc * 32 + ni * 16 + cc;
      float bv = b1[e * HID_ + col];
      #pragma unroll
      for (int r = 0; r < 4; r++){
        int rowl = mt * 64 + wr * 32 + mi * 16 + r4 + r;
        if (rowl < cnt){
          float v = gelu_tanh(acc[mi][ni][r] + bv);
          hid[(size_t)(off + rowl) * HID_ + col] = f2bf(v);
        }
      }
    }
  }
}

// ------- pipelined grouped GEMM 2 (64x64): out = x2 + p*(hid @ W2t^T + b2) -------
// grid (8, 32, D/64)
__global__ __launch_bounds__(256) void k_moe_gemm2(
    const u16* __restrict__ hid, const u16* __restrict__ W2t, const float* __restrict__ b2,
    const int* __restrict__ order, const int* __restrict__ moeI,
    const float* __restrict__ pc, const float* __restrict__ x2, float* __restrict__ out){
  int e = blockIdx.x, mt = blockIdx.y, nt = blockIdx.z;
  int cnt = moeI[e];
  if (mt * 64 >= cnt) return;
  int off = moeI[16 + e];
  __shared__ alignas(16) u16 As[2][64 * 32];
  __shared__ alignas(16) u16 Bs[2][64 * 32];
  int tid = threadIdx.x, w = tid >> 6, l = tid & 63;
  int wr = w >> 1, wc = w & 1;
  f32x4 acc[2][2];
  #pragma unroll
  for (int i = 0; i < 2; i++)
    #pragma unroll
    for (int j = 0; j < 2; j++) acc[i][j] = f32x4{0.f, 0.f, 0.f, 0.f};
  int srow = w * 16 + (l >> 2);
  int scol = (l & 3) * 8;
  int arow = off + min(mt * 64 + srow, cnt - 1);
  const u16* gA = hid + (size_t)arow * HID_ + scol;
  const u16* gB = W2t + (size_t)e * D_ * HID_ + (size_t)(nt * 64 + srow) * HID_ + scol;
  int dOff = (w * 16) * 32;
  auto STAGE = [&](int buf, int k0){
    gload_lds16(gA + k0, &As[buf][dOff]);
    gload_lds16(gB + k0, &Bs[buf][dOff]);
  };
  STAGE(0, 0);
  __syncthreads();
  int ai = (wr * 32 + (l & 15)) * 32 + 8 * (l >> 4);
  int bi = (wc * 32 + (l & 15)) * 32 + 8 * (l >> 4);
  const int nk = HID_ / 32;
  for (int t = 0; t < nk; t++){
    int cur = t & 1;
    if (t + 1 < nk) STAGE(cur ^ 1, (t + 1) * 32);
    bf16x8 af[2], bfr[2];
    #pragma unroll
    for (int mi = 0; mi < 2; mi++) af[mi] = *(const bf16x8*)&As[cur][ai + mi * 16 * 32];
    #pragma unroll
    for (int ni = 0; ni < 2; ni++) bfr[ni] = *(const bf16x8*)&Bs[cur][bi + ni * 16 * 32];
    #pragma unroll
    for (int mi = 0; mi < 2; mi++)
      #pragma unroll
      for (int ni = 0; ni < 2; ni++)
        acc[mi][ni] = __builtin_amdgcn_mfma_f32_16x16x32_bf16(af[mi], bfr[ni], acc[mi][ni], 0, 0, 0);
    __syncthreads();
  }
  int r4 = (l >> 4) * 4, cc = l & 15;
  #pragma unroll
  for (int mi = 0; mi < 2; mi++){
    #pragma unroll
    for (int r = 0; r < 4; r++){
      int rowl = mt * 64 + wr * 32 + mi * 16 + r4 + r;
      if (rowl < cnt){
        int tok = order[off + rowl];
        float pv = pc[tok];
        #pragma unroll
        for (int ni = 0; ni < 2; ni++){
          int col = nt * 64 + wc * 32 + ni * 16 + cc;
          float v = acc[mi][ni][r] + b2[e * D_ + col];
          out[(size_t)tok * D_ + col] = x2[(size_t)tok * D_ + col] + pv * v;
        }
      }
    }
  }
}

extern "C" void kernel_launch(void* const* d_in, const int* in_sizes, int n_in,
                              void* d_out, int out_size, void* d_ws, size_t ws_size,
                              hipStream_t stream){
  const float* x         = (const float*)d_in[0];
  const float* ln1_w     = (const float*)d_in[1];
  const float* ln1_b     = (const float*)d_in[2];
  const float* in_proj_w = (const float*)d_in[3];
  const float* in_proj_b = (const float*)d_in[4];
  const float* out_proj_w= (const float*)d_in[5];
  const float* out_proj_b= (const float*)d_in[6];
  const float* ln2_w     = (const float*)d_in[7];
  const float* ln2_b     = (const float*)d_in[8];
  const float* Wg        = (const float*)d_in[9];
  const float* bg        = (const float*)d_in[10];
  const float* We        = (const float*)d_in[11];
  const float* be        = (const float*)d_in[12];
  const float* W1        = (const float*)d_in[13];
  const float* b1        = (const float*)d_in[14];
  const float* W2        = (const float*)d_in[15];
  const float* b2        = (const float*)d_in[16];
  float* out = (float*)d_out;

  char* ws = (char*)d_ws;
  size_t off = 0;
  auto alloc = [&](size_t bytes) -> char* {
    char* p = ws + off;
    off += (bytes + 255) & ~(size_t)255;
    return p;
  };
  u16*   inpTh = (u16*)  alloc((size_t)3 * D_ * D_ * 2);
  u16*   inpTl = (u16*)  alloc((size_t)3 * D_ * D_ * 2);
  u16*   outpTh= (u16*)  alloc((size_t)D_ * D_ * 2);
  u16*   outpTl= (u16*)  alloc((size_t)D_ * D_ * 2);
  u16*   W1t  = (u16*)  alloc((size_t)E_ * HID_ * D_ * 2);
  u16*   W2t  = (u16*)  alloc((size_t)E_ * D_ * HID_ * 2);
  u16*   qkvh = (u16*)  alloc((size_t)NTOK * 3 * D_ * 2);
  u16*   qkvl = (u16*)  alloc((size_t)NTOK * 3 * D_ * 2);
  u16*   h1h  = (u16*)  alloc((size_t)NTOK * D_ * 2);
  u16*   h1l  = (u16*)  alloc((size_t)NTOK * D_ * 2);
  u16*   vth  = (u16*)  alloc((size_t)B_ * NH_ * DH_ * S_ * 2);
  u16*   vtl  = (u16*)  alloc((size_t)B_ * NH_ * DH_ * S_ * 2);
  float* x2   = (float*)alloc((size_t)NTOK * D_ * 4);
  u16*   h2   = (u16*)  alloc((size_t)NTOK * D_ * 2);
  int*   flat = (int*)  alloc(NTOK * 4);
  float* pc   = (float*)alloc(NTOK * 4);
  int*   order= (int*)  alloc(NTOK * 4);
  int*   moeI = (int*)  alloc(32 * 4);
  // aliases (lifetimes disjoint):
  float* h2f  = (float*)qkvh;   // written by LN2 after qkv is dead
  u16*   hid  = (u16*)qkvl;     // written by moe_gemm1 after qkv is dead
  u16*   attnh= h1h;            // h1 dead after QKV GEMM
  u16*   attnl= h1l;

  // weight prep
  k_convert_split<<<dim3((3 * D_ * D_ / 4 + 255) / 256), dim3(256), 0, stream>>>(in_proj_w, inpTh, inpTl, 3 * D_ * D_ / 4);
  k_convert_split<<<dim3((D_ * D_ / 4 + 255) / 256), dim3(256), 0, stream>>>(out_proj_w, outpTh, outpTl, D_ * D_ / 4);
  k_transpose_bf16<<<dim3(HID_ / 32, D_ / 32, E_), dim3(32, 8), 0, stream>>>(W1, W1t, D_, HID_);
  k_transpose_bf16<<<dim3(D_ / 32, HID_ / 32, E_), dim3(32, 8), 0, stream>>>(W2, W2t, HID_, D_);

  // LN1 (split output)
  k_layernorm<<<dim3(NTOK), dim3(256), 0, stream>>>(x, ln1_w, ln1_b, h1h, h1l, (float*)nullptr);
  // QKV (split GEMM -> split output)
  k_gemm3<0><<<dim3(NTOK / 64, 3 * D_ / 64), dim3(256), 0, stream>>>(
      h1h, h1l, inpTh, inpTl, in_proj_b, nullptr, qkvh, qkvl, nullptr, NTOK, 3 * D_, D_);
  // V transpose
  k_transpose_v<<<dim3(DH_ / 32, S_ / 32, B_ * NH_), dim3(32, 8), 0, stream>>>(qkvh, qkvl, vth, vtl);
  // attention (split)
  k_attn3<<<dim3(S_ / 64, B_ * NH_), dim3(256), 0, stream>>>(qkvh, qkvl, vth, vtl, attnh, attnl);
  // out-proj + residual -> x2 (f32)
  k_gemm3<1><<<dim3(NTOK / 64, D_ / 64), dim3(256), 0, stream>>>(
      attnh, attnl, outpTh, outpTl, out_proj_b, x, nullptr, nullptr, x2, NTOK, D_, D_);
  // LN2: bf16 hi for MoE + f32 for router
  k_layernorm<<<dim3(NTOK), dim3(256), 0, stream>>>(x2, ln2_w, ln2_b, h2, (u16*)nullptr, h2f);
  // router + bucketing
  k_init<<<dim3(1), dim3(64), 0, stream>>>(moeI);
  k_router<<<dim3(NTOK / 4), dim3(256), 0, stream>>>(h2f, Wg, bg, We, be, flat, pc, moeI);
  k_scan<<<dim3(1), dim3(64), 0, stream>>>(moeI);
  k_place<<<dim3(NTOK / 256), dim3(256), 0, stream>>>(flat, moeI, order);
  // grouped expert GEMMs (e = blockIdx.x -> XCD pin)
  k_moe_gemm1<<<dim3(E_, NTOK / 64, HID_ / 64), dim3(256), 0, stream>>>(h2, W1t, b1, order, moeI, hid);
  k_moe_gemm2<<<dim3(E_, NTOK / 64, D_ / 64), dim3(256), 0, stream>>>(hid, W2t, b2, order, moeI, pc, x2, out);
}

// Round 5
// 257.620 us; speedup vs baseline: 1.3678x; 1.1512x over previous
//
#include <hip/hip_runtime.h>
#include <stdint.h>

#define B_ 2
#define S_ 1024
#define D_ 768
#define NH_ 12
#define DH_ 64
#define HID_ 1536
#define G_ 4
#define EPG_ 2
#define E_ 8
#define NTOK (B_*S_)

typedef unsigned short u16;
typedef __bf16 bf16x8 __attribute__((ext_vector_type(8)));
typedef float f32x4 __attribute__((ext_vector_type(4)));
typedef u16 u16x4 __attribute__((ext_vector_type(4)));
typedef u16 u16x8 __attribute__((ext_vector_type(8)));

struct BfPair { u16 hi, lo; };

__device__ __forceinline__ u16 f2bf(float f){
  unsigned u = __builtin_bit_cast(unsigned, f);
  u += 0x7FFFu + ((u >> 16) & 1u);
  return (u16)(u >> 16);
}
__device__ __forceinline__ float bf2f(u16 h){
  unsigned u = ((unsigned)h) << 16;
  return __builtin_bit_cast(float, u);
}
__device__ __forceinline__ BfPair split_bf(float v){
  BfPair p;
  p.hi = f2bf(v);
  p.lo = f2bf(v - bf2f(p.hi));
  return p;
}
__device__ __forceinline__ float gelu_tanh(float x){
  float t = 0.7978845608028654f * (x + 0.044715f * x * x * x);
  float e = __expf(2.f * t);
  float th = 1.f - 2.f / (e + 1.f);
  return 0.5f * x * (1.f + th);
}
__device__ __forceinline__ void gload_lds16(const void* g, void* l){
  __builtin_amdgcn_global_load_lds(
      (const __attribute__((address_space(1))) void*)g,
      (__attribute__((address_space(3))) void*)l, 16, 0, 0);
}

// ---------------- convert+split f32 -> (bf16 hi, bf16 lo) ----------------
__global__ void k_convert_split(const float* __restrict__ src, u16* __restrict__ dh,
                                u16* __restrict__ dl, int n4){
  int i = blockIdx.x * blockDim.x + threadIdx.x;
  if (i < n4){
    float4 v = ((const float4*)src)[i];
    u16x4 oh, ol;
    BfPair p0 = split_bf(v.x), p1 = split_bf(v.y), p2 = split_bf(v.z), p3 = split_bf(v.w);
    oh.x = p0.hi; ol.x = p0.lo;
    oh.y = p1.hi; ol.y = p1.lo;
    oh.z = p2.hi; ol.z = p2.lo;
    oh.w = p3.hi; ol.w = p3.lo;
    ((u16x4*)dh)[i] = oh;
    ((u16x4*)dl)[i] = ol;
  }
}

// ---------------- tiled transpose + convert: src [E][R][C] f32 -> dst [E][C][R] bf16 ----
__global__ void k_transpose_bf16(const float* __restrict__ src, u16* __restrict__ dst, int R, int C){
  __shared__ float tile[32][33];
  int e = blockIdx.z;
  const float* s = src + (size_t)e * R * C;
  u16* d = dst + (size_t)e * R * C;
  int c0 = blockIdx.x * 32, r0 = blockIdx.y * 32;
  #pragma unroll
  for (int i = 0; i < 32; i += 8)
    tile[threadIdx.y + i][threadIdx.x] = s[(size_t)(r0 + threadIdx.y + i) * C + c0 + threadIdx.x];
  __syncthreads();
  #pragma unroll
  for (int i = 0; i < 32; i += 8)
    d[(size_t)(c0 + threadIdx.y + i) * R + r0 + threadIdx.x] = f2bf(tile[threadIdx.x][threadIdx.y + i]);
}

// ---------------- V transpose: qkv hi/lo [N][2304] -> vt hi/lo [BH][64][1024] ----------
__global__ void k_transpose_v(const u16* __restrict__ qh, const u16* __restrict__ ql,
                              u16* __restrict__ vth, u16* __restrict__ vtl){
  __shared__ u16 th[32][34], tl[32][34];
  int bh = blockIdx.z, b = bh / NH_, h = bh % NH_;
  int d0 = blockIdx.x * 32, s0 = blockIdx.y * 32;
  #pragma unroll
  for (int i = 0; i < 32; i += 8){
    size_t src = (size_t)(b * S_ + s0 + threadIdx.y + i) * (3 * D_) + 2 * D_ + h * DH_ + d0 + threadIdx.x;
    th[threadIdx.y + i][threadIdx.x] = qh[src];
    tl[threadIdx.y + i][threadIdx.x] = ql[src];
  }
  __syncthreads();
  #pragma unroll
  for (int i = 0; i < 32; i += 8){
    size_t dst = ((size_t)bh * DH_ + d0 + threadIdx.y + i) * S_ + s0 + threadIdx.x;
    vth[dst] = th[threadIdx.x][threadIdx.y + i];
    vtl[dst] = tl[threadIdx.x][threadIdx.y + i];
  }
}

// ---------------- layernorm: f32 in -> bf16 hi (+lo) (+f32) ----------------
__global__ __launch_bounds__(256) void k_layernorm(
    const float* __restrict__ x, const float* __restrict__ w, const float* __restrict__ b,
    u16* __restrict__ oh, u16* __restrict__ ol, float* __restrict__ of){
  int row = blockIdx.x;
  const float* xr = x + (size_t)row * D_;
  int t = threadIdx.x;
  float v0 = xr[t], v1 = xr[t + 256], v2 = xr[t + 512];
  float s = v0 + v1 + v2;
  float sq = v0 * v0 + v1 * v1 + v2 * v2;
  #pragma unroll
  for (int m = 1; m < 64; m <<= 1){ s += __shfl_xor(s, m); sq += __shfl_xor(sq, m); }
  __shared__ float ls[4], lq[4];
  int wid = t >> 6;
  if ((t & 63) == 0){ ls[wid] = s; lq[wid] = sq; }
  __syncthreads();
  s = ls[0] + ls[1] + ls[2] + ls[3];
  sq = lq[0] + lq[1] + lq[2] + lq[3];
  float mean = s * (1.f / D_);
  float var = sq * (1.f / D_) - mean * mean;
  float rstd = rsqrtf(var + 1e-5f);
  #pragma unroll
  for (int i = 0; i < 3; i++){
    int dcol = t + i * 256;
    float v = (i == 0 ? v0 : (i == 1 ? v1 : v2));
    float y = (v - mean) * rstd * w[dcol] + b[dcol];
    BfPair p = split_bf(y);
    oh[(size_t)row * D_ + dcol] = p.hi;
    if (ol) ol[(size_t)row * D_ + dcol] = p.lo;
    if (of) of[(size_t)row * D_ + dcol] = y;
  }
}

// ------- pipelined split-precision GEMM 64x64 (BK=32, swizzled ^row&3) -------
// EPI 0: store split bf16. EPI 1: store f32 + resid.
template<int EPI>
__global__ __launch_bounds__(256) void k_gemm3(
    const u16* __restrict__ Ah, const u16* __restrict__ Al,
    const u16* __restrict__ Bh, const u16* __restrict__ Bl,
    const float* __restrict__ bias, const float* __restrict__ resid,
    u16* __restrict__ outh, u16* __restrict__ outl, float* __restrict__ outf,
    int M, int N, int K){
  __shared__ alignas(16) u16 Ash[2][64 * 32];
  __shared__ alignas(16) u16 Asl[2][64 * 32];
  __shared__ alignas(16) u16 Bsh[2][64 * 32];
  __shared__ alignas(16) u16 Bsl[2][64 * 32];
  int m0 = blockIdx.x * 64, n0 = blockIdx.y * 64;
  int tid = threadIdx.x, w = tid >> 6, l = tid & 63;
  int wr = w >> 1, wc = w & 1;
  f32x4 acc[2][2];
  #pragma unroll
  for (int i = 0; i < 2; i++)
    #pragma unroll
    for (int j = 0; j < 2; j++) acc[i][j] = f32x4{0.f, 0.f, 0.f, 0.f};
  // stage: local row = w*16 + (l>>2); source chunk pre-swizzled: (l&3)^((l>>2)&3)
  int srow = w * 16 + (l >> 2);
  int scol = 8 * ((l & 3) ^ ((l >> 2) & 3));
  const u16* gAh = Ah + (size_t)(m0 + srow) * K + scol;
  const u16* gAl = Al + (size_t)(m0 + srow) * K + scol;
  const u16* gBh = Bh + (size_t)(n0 + srow) * K + scol;
  const u16* gBl = Bl + (size_t)(n0 + srow) * K + scol;
  int dOff = (w * 16) * 32;  // wave-uniform linear LDS dst
  auto STAGE = [&](int buf, int k0){
    gload_lds16(gAh + k0, &Ash[buf][dOff]);
    gload_lds16(gAl + k0, &Asl[buf][dOff]);
    gload_lds16(gBh + k0, &Bsh[buf][dOff]);
    gload_lds16(gBl + k0, &Bsl[buf][dOff]);
  };
  STAGE(0, 0);
  __syncthreads();
  int nk = K / 32;
  // read: row = (wr|wc)*32 + mi*16 + (l&15); chunk = (l>>4) ^ (row&3), row&3 == l&3
  int ca = (l >> 4) ^ (l & 3);
  int ai = (wr * 32 + (l & 15)) * 32 + 8 * ca;
  int bi = (wc * 32 + (l & 15)) * 32 + 8 * ca;
  for (int t = 0; t < nk; t++){
    int cur = t & 1;
    if (t + 1 < nk) STAGE(cur ^ 1, (t + 1) * 32);
    bf16x8 afh[2], afl[2], bfh[2], bfl[2];
    #pragma unroll
    for (int mi = 0; mi < 2; mi++){
      afh[mi] = *(const bf16x8*)&Ash[cur][ai + mi * 16 * 32];
      afl[mi] = *(const bf16x8*)&Asl[cur][ai + mi * 16 * 32];
    }
    #pragma unroll
    for (int ni = 0; ni < 2; ni++){
      bfh[ni] = *(const bf16x8*)&Bsh[cur][bi + ni * 16 * 32];
      bfl[ni] = *(const bf16x8*)&Bsl[cur][bi + ni * 16 * 32];
    }
    #pragma unroll
    for (int mi = 0; mi < 2; mi++)
      #pragma unroll
      for (int ni = 0; ni < 2; ni++){
        acc[mi][ni] = __builtin_amdgcn_mfma_f32_16x16x32_bf16(afh[mi], bfh[ni], acc[mi][ni], 0, 0, 0);
        acc[mi][ni] = __builtin_amdgcn_mfma_f32_16x16x32_bf16(afh[mi], bfl[ni], acc[mi][ni], 0, 0, 0);
        acc[mi][ni] = __builtin_amdgcn_mfma_f32_16x16x32_bf16(afl[mi], bfh[ni], acc[mi][ni], 0, 0, 0);
      }
    __syncthreads();
  }
  int r4 = (l >> 4) * 4, cc = l & 15;
  #pragma unroll
  for (int mi = 0; mi < 2; mi++){
    #pragma unroll
    for (int ni = 0; ni < 2; ni++){
      int col = n0 + wc * 32 + ni * 16 + cc;
      float bv = bias ? bias[col] : 0.f;
      #pragma unroll
      for (int r = 0; r < 4; r++){
        int row = m0 + wr * 32 + mi * 16 + r4 + r;
        float v = acc[mi][ni][r] + bv;
        if (EPI == 0){
          BfPair p = split_bf(v);
          outh[(size_t)row * N + col] = p.hi;
          outl[(size_t)row * N + col] = p.lo;
        } else {
          outf[(size_t)row * N + col] = v + resid[(size_t)row * N + col];
        }
      }
    }
  }
}

// ---------------- split-precision flash attention (swizzled ^row&7) ----------------
__global__ __launch_bounds__(256) void k_attn3(
    const u16* __restrict__ qkvh, const u16* __restrict__ qkvl,
    const u16* __restrict__ vth, const u16* __restrict__ vtl,
    u16* __restrict__ oh, u16* __restrict__ ol){
  __shared__ alignas(16) u16 Ksh[2][64 * 64];
  __shared__ alignas(16) u16 Ksl[2][64 * 64];
  __shared__ alignas(16) u16 Vsh[2][64 * 64];
  __shared__ alignas(16) u16 Vsl[2][64 * 64];
  __shared__ alignas(16) u16 Ph[4 * 16 * 64];
  __shared__ alignas(16) u16 Pl[4 * 16 * 64];
  int bh = blockIdx.y;
  int b = bh / NH_, h = bh % NH_;
  int qb = blockIdx.x;
  int tid = threadIdx.x, w = tid >> 6, l = tid & 63;
  int q0 = qb * 64 + w * 16;
  const int RS = 3 * D_;
  size_t qoff = (size_t)(b * S_ + q0 + (l & 15)) * RS + h * DH_ + 8 * (l >> 4);
  bf16x8 aqh[2], aql[2];
  aqh[0] = *(const bf16x8*)(qkvh + qoff); aqh[1] = *(const bf16x8*)(qkvh + qoff + 32);
  aql[0] = *(const bf16x8*)(qkvl + qoff); aql[1] = *(const bf16x8*)(qkvl + qoff + 32);
  f32x4 oacc[4];
  #pragma unroll
  for (int i = 0; i < 4; i++) oacc[i] = f32x4{0.f, 0.f, 0.f, 0.f};
  float mrun[4], lrun[4];
  #pragma unroll
  for (int r = 0; r < 4; r++){ mrun[r] = -1e30f; lrun[r] = 0.f; }

  // stage: local row = w*16 + (l>>3) (+8 for 2nd gload); src chunk = (l&7)^(l>>3)
  int sch = 8 * ((l & 7) ^ (l >> 3));
  size_t koff = (size_t)(b * S_ + w * 16 + (l >> 3)) * RS + D_ + h * DH_ + sch;
  const u16* Kgh = qkvh + koff;
  const u16* Kgl = qkvl + koff;
  size_t voff = ((size_t)bh * DH_ + w * 16 + (l >> 3)) * S_ + sch;
  const u16* Vgh = vth + voff;
  const u16* Vgl = vtl + voff;
  int kb0 = (w * 16) * 64;       // wave-uniform linear dst
  int kb1 = (w * 16 + 8) * 64;

  auto STAGE = [&](int buf, int kt){
    gload_lds16(Kgh + (size_t)(kt * 64) * RS, &Ksh[buf][kb0]);
    gload_lds16(Kgh + (size_t)(kt * 64 + 8) * RS, &Ksh[buf][kb1]);
    gload_lds16(Kgl + (size_t)(kt * 64) * RS, &Ksl[buf][kb0]);
    gload_lds16(Kgl + (size_t)(kt * 64 + 8) * RS, &Ksl[buf][kb1]);
    gload_lds16(Vgh + kt * 64, &Vsh[buf][kb0]);
    gload_lds16(Vgh + kt * 64 + 8 * S_, &Vsh[buf][kb1]);
    gload_lds16(Vgl + kt * 64, &Vsl[buf][kb0]);
    gload_lds16(Vgl + kt * 64 + 8 * S_, &Vsl[buf][kb1]);
  };
  STAGE(0, 0);
  __syncthreads();

  // read chunk swizzle: logical chunks (l>>4) and (l>>4)+4, key row&7 == l&7
  int c0 = (l >> 4) ^ (l & 7);
  int c1 = ((l >> 4) + 4) ^ (l & 7);

  for (int kt = 0; kt < S_ / 64; kt++){
    int cur = kt & 1;
    if (kt + 1 < S_ / 64) STAGE(cur ^ 1, kt + 1);
    // QK^T (3-term split)
    f32x4 st[4];
    #pragma unroll
    for (int nt = 0; nt < 4; nt++){
      int rbase = (nt * 16 + (l & 15)) * 64;
      bf16x8 kh0 = *(const bf16x8*)&Ksh[cur][rbase + 8 * c0];
      bf16x8 kh1 = *(const bf16x8*)&Ksh[cur][rbase + 8 * c1];
      bf16x8 kl0 = *(const bf16x8*)&Ksl[cur][rbase + 8 * c0];
      bf16x8 kl1 = *(const bf16x8*)&Ksl[cur][rbase + 8 * c1];
      f32x4 c = f32x4{0.f, 0.f, 0.f, 0.f};
      c = __builtin_amdgcn_mfma_f32_16x16x32_bf16(aqh[0], kh0, c, 0, 0, 0);
      c = __builtin_amdgcn_mfma_f32_16x16x32_bf16(aqh[1], kh1, c, 0, 0, 0);
      c = __builtin_amdgcn_mfma_f32_16x16x32_bf16(aqh[0], kl0, c, 0, 0, 0);
      c = __builtin_amdgcn_mfma_f32_16x16x32_bf16(aqh[1], kl1, c, 0, 0, 0);
      c = __builtin_amdgcn_mfma_f32_16x16x32_bf16(aql[0], kh0, c, 0, 0, 0);
      c = __builtin_amdgcn_mfma_f32_16x16x32_bf16(aql[1], kh1, c, 0, 0, 0);
      st[nt] = c;
    }
    // online softmax (rows: q = (l>>4)*4+r, cols: nt*16 + (l&15))
    float mnew[4], alpha[4];
    #pragma unroll
    for (int r = 0; r < 4; r++){
      float mx = -1e30f;
      #pragma unroll
      for (int nt = 0; nt < 4; nt++) mx = fmaxf(mx, st[nt][r] * 0.125f);
      #pragma unroll
      for (int m = 1; m < 16; m <<= 1) mx = fmaxf(mx, __shfl_xor(mx, m));
      mnew[r] = fmaxf(mrun[r], mx);
      alpha[r] = __expf(mrun[r] - mnew[r]);
      mrun[r] = mnew[r];
    }
    float pv[4][4];
    #pragma unroll
    for (int r = 0; r < 4; r++){
      float srow = 0.f;
      #pragma unroll
      for (int nt = 0; nt < 4; nt++){
        float v = __expf(st[nt][r] * 0.125f - mnew[r]);
        pv[nt][r] = v; srow += v;
      }
      #pragma unroll
      for (int m = 1; m < 16; m <<= 1) srow += __shfl_xor(srow, m);
      lrun[r] = lrun[r] * alpha[r] + srow;
    }
    #pragma unroll
    for (int nt = 0; nt < 4; nt++)
      #pragma unroll
      for (int r = 0; r < 4; r++){
        BfPair p = split_bf(pv[nt][r]);
        int prow = (l >> 4) * 4 + r;
        int pidx = (w * 1024 + prow * 64 + nt * 16 + (l & 15)) ^ ((prow & 7) << 3);
        Ph[pidx] = p.hi;
        Pl[pidx] = p.lo;
      }
    asm volatile("s_waitcnt lgkmcnt(0)" ::: "memory");
    __builtin_amdgcn_sched_barrier(0);
    #pragma unroll
    for (int t4 = 0; t4 < 4; t4++)
      #pragma unroll
      for (int r = 0; r < 4; r++) oacc[t4][r] *= alpha[r];
    int pbase = w * 1024 + (l & 15) * 64;
    bf16x8 aph0 = *(const bf16x8*)&Ph[pbase + 8 * c0];
    bf16x8 aph1 = *(const bf16x8*)&Ph[pbase + 8 * c1];
    bf16x8 apl0 = *(const bf16x8*)&Pl[pbase + 8 * c0];
    bf16x8 apl1 = *(const bf16x8*)&Pl[pbase + 8 * c1];
    #pragma unroll
    for (int dt = 0; dt < 4; dt++){
      int vbase = (dt * 16 + (l & 15)) * 64;
      bf16x8 bvh0 = *(const bf16x8*)&Vsh[cur][vbase + 8 * c0];
      bf16x8 bvh1 = *(const bf16x8*)&Vsh[cur][vbase + 8 * c1];
      bf16x8 bvl0 = *(const bf16x8*)&Vsl[cur][vbase + 8 * c0];
      bf16x8 bvl1 = *(const bf16x8*)&Vsl[cur][vbase + 8 * c1];
      oacc[dt] = __builtin_amdgcn_mfma_f32_16x16x32_bf16(aph0, bvh0, oacc[dt], 0, 0, 0);
      oacc[dt] = __builtin_amdgcn_mfma_f32_16x16x32_bf16(aph1, bvh1, oacc[dt], 0, 0, 0);
      oacc[dt] = __builtin_amdgcn_mfma_f32_16x16x32_bf16(aph0, bvl0, oacc[dt], 0, 0, 0);
      oacc[dt] = __builtin_amdgcn_mfma_f32_16x16x32_bf16(aph1, bvl1, oacc[dt], 0, 0, 0);
      oacc[dt] = __builtin_amdgcn_mfma_f32_16x16x32_bf16(apl0, bvh0, oacc[dt], 0, 0, 0);
      oacc[dt] = __builtin_amdgcn_mfma_f32_16x16x32_bf16(apl1, bvh1, oacc[dt], 0, 0, 0);
    }
    __syncthreads();
  }
  #pragma unroll
  for (int dt = 0; dt < 4; dt++)
    #pragma unroll
    for (int r = 0; r < 4; r++){
      int q = q0 + (l >> 4) * 4 + r;
      int col = h * DH_ + dt * 16 + (l & 15);
      float v = oacc[dt][r] / lrun[r];
      BfPair p = split_bf(v);
      oh[(size_t)(b * S_ + q) * D_ + col] = p.hi;
      ol[(size_t)(b * S_ + q) * D_ + col] = p.lo;
    }
}

// ---------------- router (f32) ----------------
__global__ __launch_bounds__(256) void k_router(
    const float* __restrict__ h2f, const float* __restrict__ Wg, const float* __restrict__ bg,
    const float* __restrict__ We, const float* __restrict__ be,
    int* __restrict__ flat, float* __restrict__ pc, int* __restrict__ moeI){
  int w = threadIdx.x >> 6, l = threadIdx.x & 63;
  int n = blockIdx.x * 4 + w;
  const float* hr = h2f + (size_t)n * D_;
  float pl[4] = {0.f, 0.f, 0.f, 0.f};
  for (int d = l; d < D_; d += 64){
    float hv = hr[d];
    float4 wg = *(const float4*)&Wg[d * 4];
    pl[0] += hv * wg.x; pl[1] += hv * wg.y; pl[2] += hv * wg.z; pl[3] += hv * wg.w;
  }
  #pragma unroll
  for (int m = 1; m < 64; m <<= 1)
    #pragma unroll
    for (int g = 0; g < 4; g++) pl[g] += __shfl_xor(pl[g], m);
  float lg[4];
  #pragma unroll
  for (int g = 0; g < 4; g++) lg[g] = pl[g] + bg[g];
  int gi = 0; float gm = lg[0];
  #pragma unroll
  for (int g = 1; g < 4; g++) if (lg[g] > gm){ gm = lg[g]; gi = g; }
  float gs = 0.f;
  #pragma unroll
  for (int g = 0; g < 4; g++) gs += expf(lg[g] - gm);
  float pg = 1.f / gs;
  float e0 = 0.f, e1 = 0.f;
  for (int d = l; d < D_; d += 64){
    float hv = hr[d];
    float2 we = *(const float2*)&We[((size_t)gi * D_ + d) * 2];
    e0 += hv * we.x; e1 += hv * we.y;
  }
  #pragma unroll
  for (int m = 1; m < 64; m <<= 1){ e0 += __shfl_xor(e0, m); e1 += __shfl_xor(e1, m); }
  e0 += be[gi * 2]; e1 += be[gi * 2 + 1];
  int ei; float pe;
  if (e1 > e0){ ei = 1; pe = 1.f / (1.f + expf(e0 - e1)); }
  else        { ei = 0; pe = 1.f / (1.f + expf(e1 - e0)); }
  if (l == 0){
    int f = gi * 2 + ei;
    flat[n] = f;
    pc[n] = pg * pe;
    atomicAdd(&moeI[f], 1);
  }
}

__global__ void k_init(int* moeI){ if (threadIdx.x < 16) moeI[threadIdx.x] = 0; }
__global__ void k_scan(int* moeI){
  if (threadIdx.x == 0){
    int s = 0;
    for (int e = 0; e < E_; e++){ moeI[16 + e] = s; s += moeI[e]; }
  }
}
__global__ void k_place(const int* __restrict__ flat, int* __restrict__ moeI, int* __restrict__ order){
  int n = blockIdx.x * 256 + threadIdx.x;
  if (n < NTOK){
    int f = flat[n];
    int pos = atomicAdd(&moeI[8 + f], 1);
    order[moeI[16 + f] + pos] = n;
  }
}

// ------- pipelined grouped GEMM 1 (64x64, BK=64, swizzled ^row&7): hid = gelu(h2 @ W1t^T + b1) ----
// grid (8, 32, HID/64): e = blockIdx.x -> XCD pinning
__global__ __launch_bounds__(256) void k_moe_gemm1(
    const u16* __restrict__ h2, const u16* __restrict__ W1t, const float* __restrict__ b1,
    const int* __restrict__ order, const int* __restrict__ moeI, u16* __restrict__ hid){
  int e = blockIdx.x, mt = blockIdx.y, nt = blockIdx.z;
  int cnt = moeI[e];
  if (mt * 64 >= cnt) return;
  int off = moeI[16 + e];
  __shared__ alignas(16) u16 As[2][64 * 64];
  __shared__ alignas(16) u16 Bs[2][64 * 64];
  int tid = threadIdx.x, w = tid >> 6, l = tid & 63;
  int wr = w >> 1, wc = w & 1;
  f32x4 acc[2][2];
  #pragma unroll
  for (int i = 0; i < 2; i++)
    #pragma unroll
    for (int j = 0; j < 2; j++) acc[i][j] = f32x4{0.f, 0.f, 0.f, 0.f};
  int r0 = w * 16 + (l >> 3);
  int sch = 8 * ((l & 7) ^ (l >> 3));
  int tokA0 = order[off + min(mt * 64 + r0, cnt - 1)];
  int tokA1 = order[off + min(mt * 64 + r0 + 8, cnt - 1)];
  const u16* gA0 = h2 + (size_t)tokA0 * D_ + sch;
  const u16* gA1 = h2 + (size_t)tokA1 * D_ + sch;
  const u16* gB0 = W1t + (size_t)e * HID_ * D_ + (size_t)(nt * 64 + r0) * D_ + sch;
  const u16* gB1 = gB0 + (size_t)8 * D_;
  int d0 = (w * 16) * 64, d1 = (w * 16 + 8) * 64;
  auto STAGE = [&](int buf, int k0){
    gload_lds16(gA0 + k0, &As[buf][d0]);
    gload_lds16(gA1 + k0, &As[buf][d1]);
    gload_lds16(gB0 + k0, &Bs[buf][d0]);
    gload_lds16(gB1 + k0, &Bs[buf][d1]);
  };
  STAGE(0, 0);
  __syncthreads();
  int c0 = (l >> 4) ^ (l & 7);
  int c1 = ((l >> 4) + 4) ^ (l & 7);
  const int nk = D_ / 64;
  for (int t = 0; t < nk; t++){
    int cur = t & 1;
    if (t + 1 < nk) STAGE(cur ^ 1, (t + 1) * 64);
    bf16x8 af[2][2], bfr[2][2];
    #pragma unroll
    for (int mi = 0; mi < 2; mi++){
      int rbase = (wr * 32 + mi * 16 + (l & 15)) * 64;
      af[mi][0] = *(const bf16x8*)&As[cur][rbase + 8 * c0];
      af[mi][1] = *(const bf16x8*)&As[cur][rbase + 8 * c1];
    }
    #pragma unroll
    for (int ni = 0; ni < 2; ni++){
      int rbase = (wc * 32 + ni * 16 + (l & 15)) * 64;
      bfr[ni][0] = *(const bf16x8*)&Bs[cur][rbase + 8 * c0];
      bfr[ni][1] = *(const bf16x8*)&Bs[cur][rbase + 8 * c1];
    }
    #pragma unroll
    for (int mi = 0; mi < 2; mi++)
      #pragma unroll
      for (int ni = 0; ni < 2; ni++){
        acc[mi][ni] = __builtin_amdgcn_mfma_f32_16x16x32_bf16(af[mi][0], bfr[ni][0], acc[mi][ni], 0, 0, 0);
        acc[mi][ni] = __builtin_amdgcn_mfma_f32_16x16x32_bf16(af[mi][1], bfr[ni][1], acc[mi][ni], 0, 0, 0);
      }
    __syncthreads();
  }
  int r4 = (l >> 4) * 4, cc = l & 15;
  #pragma unroll
  for (int mi = 0; mi < 2; mi++){
    #pragma unroll
    for (int ni = 0; ni < 2; ni++){
      int col = nt * 64 + wc * 32 + ni * 16 + cc;
      float bv = b1[e * HID_ + col];
      #pragma unroll
      for (int r = 0; r < 4; r++){
        int rowl = mt * 64 + wr * 32 + mi * 16 + r4 + r;
        if (rowl < cnt){
          float v = gelu_tanh(acc[mi][ni][r] + bv);
          hid[(size_t)(off + rowl) * HID_ + col] = f2bf(v);
        }
      }
    }
  }
}

// ------- pipelined grouped GEMM 2 (64x64, BK=64, swizzled): out = x2 + p*(hid @ W2t^T + b2) ----
// grid (8, 32, D/64)
__global__ __launch_bounds__(256) void k_moe_gemm2(
    const u16* __restrict__ hid, const u16* __restrict__ W2t, const float* __restrict__ b2,
    const int* __restrict__ order, const int* __restrict__ moeI,
    const float* __restrict__ pc, const float* __restrict__ x2, float* __restrict__ out){
  int e = blockIdx.x, mt = blockIdx.y, nt = blockIdx.z;
  int cnt = moeI[e];
  if (mt * 64 >= cnt) return;
  int off = moeI[16 + e];
  __shared__ alignas(16) u16 As[2][64 * 64];
  __shared__ alignas(16) u16 Bs[2][64 * 64];
  int tid = threadIdx.x, w = tid >> 6, l = tid & 63;
  int wr = w >> 1, wc = w & 1;
  f32x4 acc[2][2];
  #pragma unroll
  for (int i = 0; i < 2; i++)
    #pragma unroll
    for (int j = 0; j < 2; j++) acc[i][j] = f32x4{0.f, 0.f, 0.f, 0.f};
  int r0 = w * 16 + (l >> 3);
  int sch = 8 * ((l & 7) ^ (l >> 3));
  int ar0 = off + min(mt * 64 + r0, cnt - 1);
  int ar1 = off + min(mt * 64 + r0 + 8, cnt - 1);
  const u16* gA0 = hid + (size_t)ar0 * HID_ + sch;
  const u16* gA1 = hid + (size_t)ar1 * HID_ + sch;
  const u16* gB0 = W2t + (size_t)e * D_ * HID_ + (size_t)(nt * 64 + r0) * HID_ + sch;
  const u16* gB1 = gB0 + (size_t)8 * HID_;
  int d0 = (w * 16) * 64, d1 = (w * 16 + 8) * 64;
  auto STAGE = [&](int buf, int k0){
    gload_lds16(gA0 + k0, &As[buf][d0]);
    gload_lds16(gA1 + k0, &As[buf][d1]);
    gload_lds16(gB0 + k0, &Bs[buf][d0]);
    gload_lds16(gB1 + k0, &Bs[buf][d1]);
  };
  STAGE(0, 0);
  __syncthreads();
  int c0 = (l >> 4) ^ (l & 7);
  int c1 = ((l >> 4) + 4) ^ (l & 7);
  const int nk = HID_ / 64;
  for (int t = 0; t < nk; t++){
    int cur = t & 1;
    if (t + 1 < nk) STAGE(cur ^ 1, (t + 1) * 64);
    bf16x8 af[2][2], bfr[2][2];
    #pragma unroll
    for (int mi = 0; mi < 2; mi++){
      int rbase = (wr * 32 + mi * 16 + (l & 15)) * 64;
      af[mi][0] = *(const bf16x8*)&As[cur][rbase + 8 * c0];
      af[mi][1] = *(const bf16x8*)&As[cur][rbase + 8 * c1];
    }
    #pragma unroll
    for (int ni = 0; ni < 2; ni++){
      int rbase = (wc * 32 + ni * 16 + (l & 15)) * 64;
      bfr[ni][0] = *(const bf16x8*)&Bs[cur][rbase + 8 * c0];
      bfr[ni][1] = *(const bf16x8*)&Bs[cur][rbase + 8 * c1];
    }
    #pragma unroll
    for (int mi = 0; mi < 2; mi++)
      #pragma unroll
      for (int ni = 0; ni < 2; ni++){
        acc[mi][ni] = __builtin_amdgcn_mfma_f32_16x16x32_bf16(af[mi][0], bfr[ni][0], acc[mi][ni], 0, 0, 0);
        acc[mi][ni] = __builtin_amdgcn_mfma_f32_16x16x32_bf16(af[mi][1], bfr[ni][1], acc[mi][ni], 0, 0, 0);
      }
    __syncthreads();
  }
  int r4 = (l >> 4) * 4, cc = l & 15;
  #pragma unroll
  for (int mi = 0; mi < 2; mi++){
    #pragma unroll
    for (int r = 0; r < 4; r++){
      int rowl = mt * 64 + wr * 32 + mi * 16 + r4 + r;
      if (rowl < cnt){
        int tok = order[off + rowl];
        float pv = pc[tok];
        #pragma unroll
        for (int ni = 0; ni < 2; ni++){
          int col = nt * 64 + wc * 32 + ni * 16 + cc;
          float v = acc[mi][ni][r] + b2[e * D_ + col];
          out[(size_t)tok * D_ + col] = x2[(size_t)tok * D_ + col] + pv * v;
        }
      }
    }
  }
}

extern "C" void kernel_launch(void* const* d_in, const int* in_sizes, int n_in,
                              void* d_out, int out_size, void* d_ws, size_t ws_size,
                              hipStream_t stream){
  const float* x         = (const float*)d_in[0];
  const float* ln1_w     = (const float*)d_in[1];
  const float* ln1_b     = (const float*)d_in[2];
  const float* in_proj_w = (const float*)d_in[3];
  const float* in_proj_b = (const float*)d_in[4];
  const float* out_proj_w= (const float*)d_in[5];
  const float* out_proj_b= (const float*)d_in[6];
  const float* ln2_w     = (const float*)d_in[7];
  const float* ln2_b     = (const float*)d_in[8];
  const float* Wg        = (const float*)d_in[9];
  const float* bg        = (const float*)d_in[10];
  const float* We        = (const float*)d_in[11];
  const float* be        = (const float*)d_in[12];
  const float* W1        = (const float*)d_in[13];
  const float* b1        = (const float*)d_in[14];
  const float* W2        = (const float*)d_in[15];
  const float* b2        = (const float*)d_in[16];
  float* out = (float*)d_out;

  char* ws = (char*)d_ws;
  size_t off = 0;
  auto alloc = [&](size_t bytes) -> char* {
    char* p = ws + off;
    off += (bytes + 255) & ~(size_t)255;
    return p;
  };
  u16*   inpTh = (u16*)  alloc((size_t)3 * D_ * D_ * 2);
  u16*   inpTl = (u16*)  alloc((size_t)3 * D_ * D_ * 2);
  u16*   outpTh= (u16*)  alloc((size_t)D_ * D_ * 2);
  u16*   outpTl= (u16*)  alloc((size_t)D_ * D_ * 2);
  u16*   W1t  = (u16*)  alloc((size_t)E_ * HID_ * D_ * 2);
  u16*   W2t  = (u16*)  alloc((size_t)E_ * D_ * HID_ * 2);
  u16*   qkvh = (u16*)  alloc((size_t)NTOK * 3 * D_ * 2);
  u16*   qkvl = (u16*)  alloc((size_t)NTOK * 3 * D_ * 2);
  u16*   h1h  = (u16*)  alloc((size_t)NTOK * D_ * 2);
  u16*   h1l  = (u16*)  alloc((size_t)NTOK * D_ * 2);
  u16*   vth  = (u16*)  alloc((size_t)B_ * NH_ * DH_ * S_ * 2);
  u16*   vtl  = (u16*)  alloc((size_t)B_ * NH_ * DH_ * S_ * 2);
  float* x2   = (float*)alloc((size_t)NTOK * D_ * 4);
  u16*   h2   = (u16*)  alloc((size_t)NTOK * D_ * 2);
  int*   flat = (int*)  alloc(NTOK * 4);
  float* pc   = (float*)alloc(NTOK * 4);
  int*   order= (int*)  alloc(NTOK * 4);
  int*   moeI = (int*)  alloc(32 * 4);
  // aliases (lifetimes disjoint):
  float* h2f  = (float*)qkvh;   // written by LN2 after qkv is dead
  u16*   hid  = (u16*)qkvl;     // written by moe_gemm1 after qkv is dead
  u16*   attnh= h1h;            // h1 dead after QKV GEMM
  u16*   attnl= h1l;

  // weight prep
  k_convert_split<<<dim3((3 * D_ * D_ / 4 + 255) / 256), dim3(256), 0, stream>>>(in_proj_w, inpTh, inpTl, 3 * D_ * D_ / 4);
  k_convert_split<<<dim3((D_ * D_ / 4 + 255) / 256), dim3(256), 0, stream>>>(out_proj_w, outpTh, outpTl, D_ * D_ / 4);
  k_transpose_bf16<<<dim3(HID_ / 32, D_ / 32, E_), dim3(32, 8), 0, stream>>>(W1, W1t, D_, HID_);
  k_transpose_bf16<<<dim3(D_ / 32, HID_ / 32, E_), dim3(32, 8), 0, stream>>>(W2, W2t, HID_, D_);

  // LN1 (split output)
  k_layernorm<<<dim3(NTOK), dim3(256), 0, stream>>>(x, ln1_w, ln1_b, h1h, h1l, (float*)nullptr);
  // QKV (split GEMM -> split output)
  k_gemm3<0><<<dim3(NTOK / 64, 3 * D_ / 64), dim3(256), 0, stream>>>(
      h1h, h1l, inpTh, inpTl, in_proj_b, nullptr, qkvh, qkvl, nullptr, NTOK, 3 * D_, D_);
  // V transpose
  k_transpose_v<<<dim3(DH_ / 32, S_ / 32, B_ * NH_), dim3(32, 8), 0, stream>>>(qkvh, qkvl, vth, vtl);
  // attention (split)
  k_attn3<<<dim3(S_ / 64, B_ * NH_), dim3(256), 0, stream>>>(qkvh, qkvl, vth, vtl, attnh, attnl);
  // out-proj + residual -> x2 (f32)
  k_gemm3<1><<<dim3(NTOK / 64, D_ / 64), dim3(256), 0, stream>>>(
      attnh, attnl, outpTh, outpTl, out_proj_b, x, nullptr, nullptr, x2, NTOK, D_, D_);
  // LN2: bf16 hi for MoE + f32 for router
  k_layernorm<<<dim3(NTOK), dim3(256), 0, stream>>>(x2, ln2_w, ln2_b, h2, (u16*)nullptr, h2f);
  // router + bucketing
  k_init<<<dim3(1), dim3(64), 0, stream>>>(moeI);
  k_router<<<dim3(NTOK / 4), dim3(256), 0, stream>>>(h2f, Wg, bg, We, be, flat, pc, moeI);
  k_scan<<<dim3(1), dim3(64), 0, stream>>>(moeI);
  k_place<<<dim3(NTOK / 256), dim3(256), 0, stream>>>(flat, moeI, order);
  // grouped expert GEMMs (e = blockIdx.x -> XCD pin)
  k_moe_gemm1<<<dim3(E_, NTOK / 64, HID_ / 64), dim3(256), 0, stream>>>(h2, W1t, b1, order, moeI, hid);
  k_moe_gemm2<<<dim3(E_, NTOK / 64, D_ / 64), dim3(256), 0, stream>>>(hid, W2t, b2, order, moeI, pc, x2, out);
}

// Round 6
// 217.485 us; speedup vs baseline: 1.6202x; 1.1845x over previous
//
#include <hip/hip_runtime.h>
#include <stdint.h>

#define B_ 2
#define S_ 1024
#define D_ 768
#define NH_ 12
#define DH_ 64
#define HID_ 1536
#define G_ 4
#define EPG_ 2
#define E_ 8
#define NTOK (B_*S_)
#define NGRP (B_*NH_*16)   // 384 (bh x qb) groups

typedef unsigned short u16;
typedef __bf16 bf16x8 __attribute__((ext_vector_type(8)));
typedef float f32x4 __attribute__((ext_vector_type(4)));
typedef u16 u16x4 __attribute__((ext_vector_type(4)));
typedef u16 u16x8 __attribute__((ext_vector_type(8)));

struct BfPair { u16 hi, lo; };

__device__ __forceinline__ u16 f2bf(float f){
  unsigned u = __builtin_bit_cast(unsigned, f);
  u += 0x7FFFu + ((u >> 16) & 1u);
  return (u16)(u >> 16);
}
__device__ __forceinline__ float bf2f(u16 h){
  unsigned u = ((unsigned)h) << 16;
  return __builtin_bit_cast(float, u);
}
__device__ __forceinline__ BfPair split_bf(float v){
  BfPair p;
  p.hi = f2bf(v);
  p.lo = f2bf(v - bf2f(p.hi));
  return p;
}
__device__ __forceinline__ float gelu_tanh(float x){
  float t = 0.7978845608028654f * (x + 0.044715f * x * x * x);
  float e = __expf(2.f * t);
  float th = 1.f - 2.f / (e + 1.f);
  return 0.5f * x * (1.f + th);
}
__device__ __forceinline__ void gload_lds16(const void* g, void* l){
  __builtin_amdgcn_global_load_lds(
      (const __attribute__((address_space(1))) void*)g,
      (__attribute__((address_space(3))) void*)l, 16, 0, 0);
}

// ---------------- fused weight prep: converts + transposes in one kernel ----------------
// blocks: [0,1728) conv in_proj; [1728,2304) conv out_proj;
//         [2304,11520) transpose W1 (R=768,C=1536); [11520,20736) transpose W2 (R=1536,C=768)
__global__ __launch_bounds__(256) void k_prep(
    const float* __restrict__ in_proj_w, const float* __restrict__ out_proj_w,
    const float* __restrict__ W1, const float* __restrict__ W2,
    u16* __restrict__ inpTh, u16* __restrict__ inpTl,
    u16* __restrict__ outpTh, u16* __restrict__ outpTl,
    u16* __restrict__ W1t, u16* __restrict__ W2t){
  __shared__ float tile[32][33];
  int bid = blockIdx.x, t = threadIdx.x;
  if (bid < 2304){
    const float* src; u16 *dh, *dl; int i;
    if (bid < 1728){ src = in_proj_w; dh = inpTh; dl = inpTl; i = bid * 256 + t; }
    else           { src = out_proj_w; dh = outpTh; dl = outpTl; i = (bid - 1728) * 256 + t; }
    float4 v = ((const float4*)src)[i];
    u16x4 oh, ol;
    BfPair p0 = split_bf(v.x), p1 = split_bf(v.y), p2 = split_bf(v.z), p3 = split_bf(v.w);
    oh.x = p0.hi; ol.x = p0.lo; oh.y = p1.hi; ol.y = p1.lo;
    oh.z = p2.hi; ol.z = p2.lo; oh.w = p3.hi; ol.w = p3.lo;
    ((u16x4*)dh)[i] = oh;
    ((u16x4*)dl)[i] = ol;
  } else {
    const float* src; u16* dst; int R, C, cx, cy, e;
    if (bid < 11520){
      int r = bid - 2304; e = r / 1152; r %= 1152;
      R = D_; C = HID_; cx = r % 48; cy = r / 48;
      src = W1; dst = W1t;
    } else {
      int r = bid - 11520; e = r / 1152; r %= 1152;
      R = HID_; C = D_; cx = r % 24; cy = r / 24;
      src = W2; dst = W2t;
    }
    const float* s = src + (size_t)e * R * C;
    u16* d = dst + (size_t)e * R * C;
    int c0 = cx * 32, r0 = cy * 32;
    int tx = t & 31, ty = t >> 5;
    #pragma unroll
    for (int i = 0; i < 32; i += 8)
      tile[ty + i][tx] = s[(size_t)(r0 + ty + i) * C + c0 + tx];
    __syncthreads();
    #pragma unroll
    for (int i = 0; i < 32; i += 8)
      d[(size_t)(c0 + ty + i) * R + r0 + tx] = f2bf(tile[tx][ty + i]);
  }
}

// ---------------- V transpose: qkv hi/lo [N][2304] -> vt hi/lo [BH][64][1024] ----------
__global__ void k_transpose_v(const u16* __restrict__ qh, const u16* __restrict__ ql,
                              u16* __restrict__ vth, u16* __restrict__ vtl){
  __shared__ u16 th[32][34], tl[32][34];
  int bh = blockIdx.z, b = bh / NH_, h = bh % NH_;
  int d0 = blockIdx.x * 32, s0 = blockIdx.y * 32;
  #pragma unroll
  for (int i = 0; i < 32; i += 8){
    size_t src = (size_t)(b * S_ + s0 + threadIdx.y + i) * (3 * D_) + 2 * D_ + h * DH_ + d0 + threadIdx.x;
    th[threadIdx.y + i][threadIdx.x] = qh[src];
    tl[threadIdx.y + i][threadIdx.x] = ql[src];
  }
  __syncthreads();
  #pragma unroll
  for (int i = 0; i < 32; i += 8){
    size_t dst = ((size_t)bh * DH_ + d0 + threadIdx.y + i) * S_ + s0 + threadIdx.x;
    vth[dst] = th[threadIdx.x][threadIdx.y + i];
    vtl[dst] = tl[threadIdx.x][threadIdx.y + i];
  }
}

// ---------------- layernorm: f32 in -> bf16 hi (+lo) (+f32) ----------------
__global__ __launch_bounds__(256) void k_layernorm(
    const float* __restrict__ x, const float* __restrict__ w, const float* __restrict__ b,
    u16* __restrict__ oh, u16* __restrict__ ol, float* __restrict__ of){
  int row = blockIdx.x;
  const float* xr = x + (size_t)row * D_;
  int t = threadIdx.x;
  float v0 = xr[t], v1 = xr[t + 256], v2 = xr[t + 512];
  float s = v0 + v1 + v2;
  float sq = v0 * v0 + v1 * v1 + v2 * v2;
  #pragma unroll
  for (int m = 1; m < 64; m <<= 1){ s += __shfl_xor(s, m); sq += __shfl_xor(sq, m); }
  __shared__ float ls[4], lq[4];
  int wid = t >> 6;
  if ((t & 63) == 0){ ls[wid] = s; lq[wid] = sq; }
  __syncthreads();
  s = ls[0] + ls[1] + ls[2] + ls[3];
  sq = lq[0] + lq[1] + lq[2] + lq[3];
  float mean = s * (1.f / D_);
  float var = sq * (1.f / D_) - mean * mean;
  float rstd = rsqrtf(var + 1e-5f);
  #pragma unroll
  for (int i = 0; i < 3; i++){
    int dcol = t + i * 256;
    float v = (i == 0 ? v0 : (i == 1 ? v1 : v2));
    float y = (v - mean) * rstd * w[dcol] + b[dcol];
    BfPair p = split_bf(y);
    oh[(size_t)row * D_ + dcol] = p.hi;
    if (ol) ol[(size_t)row * D_ + dcol] = p.lo;
    if (of) of[(size_t)row * D_ + dcol] = y;
  }
}

// ------- pipelined split-precision GEMM 64x64 (BK=32, swizzled ^row&3) -------
template<int EPI>
__global__ __launch_bounds__(256) void k_gemm3(
    const u16* __restrict__ Ah, const u16* __restrict__ Al,
    const u16* __restrict__ Bh, const u16* __restrict__ Bl,
    const float* __restrict__ bias, const float* __restrict__ resid,
    u16* __restrict__ outh, u16* __restrict__ outl, float* __restrict__ outf,
    int M, int N, int K){
  __shared__ alignas(16) u16 Ash[2][64 * 32];
  __shared__ alignas(16) u16 Asl[2][64 * 32];
  __shared__ alignas(16) u16 Bsh[2][64 * 32];
  __shared__ alignas(16) u16 Bsl[2][64 * 32];
  int m0 = blockIdx.x * 64, n0 = blockIdx.y * 64;
  int tid = threadIdx.x, w = tid >> 6, l = tid & 63;
  int wr = w >> 1, wc = w & 1;
  f32x4 acc[2][2];
  #pragma unroll
  for (int i = 0; i < 2; i++)
    #pragma unroll
    for (int j = 0; j < 2; j++) acc[i][j] = f32x4{0.f, 0.f, 0.f, 0.f};
  int srow = w * 16 + (l >> 2);
  int scol = 8 * ((l & 3) ^ ((l >> 2) & 3));
  const u16* gAh = Ah + (size_t)(m0 + srow) * K + scol;
  const u16* gAl = Al + (size_t)(m0 + srow) * K + scol;
  const u16* gBh = Bh + (size_t)(n0 + srow) * K + scol;
  const u16* gBl = Bl + (size_t)(n0 + srow) * K + scol;
  int dOff = (w * 16) * 32;
  auto STAGE = [&](int buf, int k0){
    gload_lds16(gAh + k0, &Ash[buf][dOff]);
    gload_lds16(gAl + k0, &Asl[buf][dOff]);
    gload_lds16(gBh + k0, &Bsh[buf][dOff]);
    gload_lds16(gBl + k0, &Bsl[buf][dOff]);
  };
  STAGE(0, 0);
  __syncthreads();
  int nk = K / 32;
  int ca = (l >> 4) ^ (l & 3);
  int ai = (wr * 32 + (l & 15)) * 32 + 8 * ca;
  int bi = (wc * 32 + (l & 15)) * 32 + 8 * ca;
  for (int t = 0; t < nk; t++){
    int cur = t & 1;
    if (t + 1 < nk) STAGE(cur ^ 1, (t + 1) * 32);
    bf16x8 afh[2], afl[2], bfh[2], bfl[2];
    #pragma unroll
    for (int mi = 0; mi < 2; mi++){
      afh[mi] = *(const bf16x8*)&Ash[cur][ai + mi * 16 * 32];
      afl[mi] = *(const bf16x8*)&Asl[cur][ai + mi * 16 * 32];
    }
    #pragma unroll
    for (int ni = 0; ni < 2; ni++){
      bfh[ni] = *(const bf16x8*)&Bsh[cur][bi + ni * 16 * 32];
      bfl[ni] = *(const bf16x8*)&Bsl[cur][bi + ni * 16 * 32];
    }
    #pragma unroll
    for (int mi = 0; mi < 2; mi++)
      #pragma unroll
      for (int ni = 0; ni < 2; ni++){
        acc[mi][ni] = __builtin_amdgcn_mfma_f32_16x16x32_bf16(afh[mi], bfh[ni], acc[mi][ni], 0, 0, 0);
        acc[mi][ni] = __builtin_amdgcn_mfma_f32_16x16x32_bf16(afh[mi], bfl[ni], acc[mi][ni], 0, 0, 0);
        acc[mi][ni] = __builtin_amdgcn_mfma_f32_16x16x32_bf16(afl[mi], bfh[ni], acc[mi][ni], 0, 0, 0);
      }
    __syncthreads();
  }
  int r4 = (l >> 4) * 4, cc = l & 15;
  #pragma unroll
  for (int mi = 0; mi < 2; mi++){
    #pragma unroll
    for (int ni = 0; ni < 2; ni++){
      int col = n0 + wc * 32 + ni * 16 + cc;
      float bv = bias ? bias[col] : 0.f;
      #pragma unroll
      for (int r = 0; r < 4; r++){
        int row = m0 + wr * 32 + mi * 16 + r4 + r;
        float v = acc[mi][ni][r] + bv;
        if (EPI == 0){
          BfPair p = split_bf(v);
          outh[(size_t)row * N + col] = p.hi;
          outl[(size_t)row * N + col] = p.lo;
        } else {
          outf[(size_t)row * N + col] = v + resid[(size_t)row * N + col];
        }
      }
    }
  }
}

// ---------------- split-precision flash attention, split-K x2, KVBLK=32 ----------------
// grid (bh=24, qb=16, ks=2): XCD = bh%8 for all blocks of one head
__global__ __launch_bounds__(256) void k_attn3(
    const u16* __restrict__ qkvh, const u16* __restrict__ qkvl,
    const u16* __restrict__ vth, const u16* __restrict__ vtl,
    float* __restrict__ po0, float* __restrict__ po1,
    float* __restrict__ pm, float* __restrict__ plsum){
  __shared__ alignas(16) u16 Ksh[2][32 * 64];
  __shared__ alignas(16) u16 Ksl[2][32 * 64];
  __shared__ alignas(16) u16 Vsh[2][64 * 32];
  __shared__ alignas(16) u16 Vsl[2][64 * 32];
  __shared__ alignas(16) u16 Ph[4 * 16 * 32];
  __shared__ alignas(16) u16 Pl[4 * 16 * 32];
  int bh = blockIdx.x, qb = blockIdx.y, ks = blockIdx.z;
  int b = bh / NH_, h = bh % NH_;
  int g = bh * 16 + qb;
  int tid = threadIdx.x, w = tid >> 6, l = tid & 63;
  int q0 = qb * 64 + w * 16;
  const int RS = 3 * D_;
  size_t qoff = (size_t)(b * S_ + q0 + (l & 15)) * RS + h * DH_ + 8 * (l >> 4);
  bf16x8 aqh[2], aql[2];
  aqh[0] = *(const bf16x8*)(qkvh + qoff); aqh[1] = *(const bf16x8*)(qkvh + qoff + 32);
  aql[0] = *(const bf16x8*)(qkvl + qoff); aql[1] = *(const bf16x8*)(qkvl + qoff + 32);
  f32x4 oacc[4];
  #pragma unroll
  for (int i = 0; i < 4; i++) oacc[i] = f32x4{0.f, 0.f, 0.f, 0.f};
  float mrun[4], lrun[4];
  #pragma unroll
  for (int r = 0; r < 4; r++){ mrun[r] = -1e30f; lrun[r] = 0.f; }

  // stage addresses (pre-swizzled global source, linear LDS dest)
  size_t koff = (size_t)(b * S_ + w * 8 + (l >> 3)) * RS + D_ + h * DH_ + 8 * ((l & 7) ^ (l >> 3));
  const u16* Kgh = qkvh + koff;
  const u16* Kgl = qkvl + koff;
  size_t voff = ((size_t)bh * DH_ + w * 16 + (l >> 2)) * S_ + 8 * ((l & 3) ^ ((l >> 2) & 3));
  const u16* Vgh = vth + voff;
  const u16* Vgl = vtl + voff;
  int wdst = w * 512;

  auto STAGE = [&](int buf, int akt){
    gload_lds16(Kgh + (size_t)(akt * 32) * RS, &Ksh[buf][wdst]);
    gload_lds16(Kgl + (size_t)(akt * 32) * RS, &Ksl[buf][wdst]);
    gload_lds16(Vgh + akt * 32, &Vsh[buf][wdst]);
    gload_lds16(Vgl + akt * 32, &Vsl[buf][wdst]);
  };
  int kt0 = ks * 16;
  STAGE(0, kt0);
  __syncthreads();

  int ck0 = (l >> 4) ^ (l & 7);
  int ck1 = ck0 ^ 4;
  int cv = (l >> 4) ^ (l & 3);

  for (int kt = 0; kt < 16; kt++){
    int cur = kt & 1;
    if (kt + 1 < 16) STAGE(cur ^ 1, kt0 + kt + 1);
    // QK^T (3-term split)
    f32x4 st[2];
    #pragma unroll
    for (int nt = 0; nt < 2; nt++){
      int rbase = (nt * 16 + (l & 15)) * 64;
      bf16x8 kh0 = *(const bf16x8*)&Ksh[cur][rbase + 8 * ck0];
      bf16x8 kh1 = *(const bf16x8*)&Ksh[cur][rbase + 8 * ck1];
      bf16x8 kl0 = *(const bf16x8*)&Ksl[cur][rbase + 8 * ck0];
      bf16x8 kl1 = *(const bf16x8*)&Ksl[cur][rbase + 8 * ck1];
      f32x4 c = f32x4{0.f, 0.f, 0.f, 0.f};
      c = __builtin_amdgcn_mfma_f32_16x16x32_bf16(aqh[0], kh0, c, 0, 0, 0);
      c = __builtin_amdgcn_mfma_f32_16x16x32_bf16(aqh[1], kh1, c, 0, 0, 0);
      c = __builtin_amdgcn_mfma_f32_16x16x32_bf16(aqh[0], kl0, c, 0, 0, 0);
      c = __builtin_amdgcn_mfma_f32_16x16x32_bf16(aqh[1], kl1, c, 0, 0, 0);
      c = __builtin_amdgcn_mfma_f32_16x16x32_bf16(aql[0], kh0, c, 0, 0, 0);
      c = __builtin_amdgcn_mfma_f32_16x16x32_bf16(aql[1], kh1, c, 0, 0, 0);
      st[nt] = c;
    }
    // online softmax
    float mnew[4], alpha[4];
    #pragma unroll
    for (int r = 0; r < 4; r++){
      float mx = fmaxf(st[0][r], st[1][r]) * 0.125f;
      #pragma unroll
      for (int m = 1; m < 16; m <<= 1) mx = fmaxf(mx, __shfl_xor(mx, m));
      mnew[r] = fmaxf(mrun[r], mx);
      alpha[r] = __expf(mrun[r] - mnew[r]);
      mrun[r] = mnew[r];
    }
    float pv[2][4];
    #pragma unroll
    for (int r = 0; r < 4; r++){
      float srow = 0.f;
      #pragma unroll
      for (int nt = 0; nt < 2; nt++){
        float v = __expf(st[nt][r] * 0.125f - mnew[r]);
        pv[nt][r] = v; srow += v;
      }
      #pragma unroll
      for (int m = 1; m < 16; m <<= 1) srow += __shfl_xor(srow, m);
      lrun[r] = lrun[r] * alpha[r] + srow;
    }
    #pragma unroll
    for (int nt = 0; nt < 2; nt++)
      #pragma unroll
      for (int r = 0; r < 4; r++){
        BfPair p = split_bf(pv[nt][r]);
        int q = (l >> 4) * 4 + r;
        int col = nt * 16 + (l & 15);
        int pidx = wdst + q * 32 + (((col >> 3) ^ (q & 3)) << 3) + (col & 7);
        Ph[pidx] = p.hi;
        Pl[pidx] = p.lo;
      }
    asm volatile("s_waitcnt lgkmcnt(0)" ::: "memory");
    __builtin_amdgcn_sched_barrier(0);
    #pragma unroll
    for (int t4 = 0; t4 < 4; t4++)
      #pragma unroll
      for (int r = 0; r < 4; r++) oacc[t4][r] *= alpha[r];
    int pb = wdst + (l & 15) * 32 + 8 * cv;
    bf16x8 aph = *(const bf16x8*)&Ph[pb];
    bf16x8 apl = *(const bf16x8*)&Pl[pb];
    #pragma unroll
    for (int dt = 0; dt < 4; dt++){
      int vb = (dt * 16 + (l & 15)) * 32 + 8 * cv;
      bf16x8 bvh = *(const bf16x8*)&Vsh[cur][vb];
      bf16x8 bvl = *(const bf16x8*)&Vsl[cur][vb];
      oacc[dt] = __builtin_amdgcn_mfma_f32_16x16x32_bf16(aph, bvh, oacc[dt], 0, 0, 0);
      oacc[dt] = __builtin_amdgcn_mfma_f32_16x16x32_bf16(aph, bvl, oacc[dt], 0, 0, 0);
      oacc[dt] = __builtin_amdgcn_mfma_f32_16x16x32_bf16(apl, bvh, oacc[dt], 0, 0, 0);
    }
    __syncthreads();
  }
  // partial epilogue: unnormalized O + m + l
  float* po = ks ? po1 : po0;
  #pragma unroll
  for (int dt = 0; dt < 4; dt++)
    #pragma unroll
    for (int r = 0; r < 4; r++){
      int qloc = w * 16 + (l >> 4) * 4 + r;
      int d = dt * 16 + (l & 15);
      po[((size_t)(g * 64 + qloc)) * 64 + d] = oacc[dt][r];
    }
  if ((l & 15) == 0){
    #pragma unroll
    for (int r = 0; r < 4; r++){
      int qloc = w * 16 + (l >> 4) * 4 + r;
      pm[(ks * NGRP + g) * 64 + qloc] = mrun[r];
      plsum[(ks * NGRP + g) * 64 + qloc] = lrun[r];
    }
  }
}

// ---------------- attn split-K merge -> split bf16 attn output ----------------
__global__ __launch_bounds__(256) void k_attn_merge(
    const float* __restrict__ po0, const float* __restrict__ po1,
    const float* __restrict__ pm, const float* __restrict__ plsum,
    u16* __restrict__ oh, u16* __restrict__ ol){
  int bh = blockIdx.x, qb = blockIdx.y;
  int b = bh / NH_, h = bh % NH_;
  int g = bh * 16 + qb;
  int t = threadIdx.x;
  int q = t >> 2, d0 = (t & 3) * 16;
  float m0 = pm[g * 64 + q],      m1 = pm[NGRP * 64 + g * 64 + q];
  float l0 = plsum[g * 64 + q],   l1 = plsum[NGRP * 64 + g * 64 + q];
  float M = fmaxf(m0, m1);
  float a0 = __expf(m0 - M), a1 = __expf(m1 - M);
  float rcp = 1.f / (l0 * a0 + l1 * a1);
  size_t base = ((size_t)(g * 64 + q)) * 64 + d0;
  size_t orow = (size_t)(b * S_ + qb * 64 + q) * D_ + h * DH_ + d0;
  #pragma unroll
  for (int j = 0; j < 16; j++){
    float v = (po0[base + j] * a0 + po1[base + j] * a1) * rcp;
    BfPair p = split_bf(v);
    oh[orow + j] = p.hi;
    ol[orow + j] = p.lo;
  }
}

// ---------------- router (f32, no atomics) ----------------
__global__ __launch_bounds__(256) void k_router(
    const float* __restrict__ h2f, const float* __restrict__ Wg, const float* __restrict__ bg,
    const float* __restrict__ We, const float* __restrict__ be,
    int* __restrict__ flat, float* __restrict__ pc){
  int w = threadIdx.x >> 6, l = threadIdx.x & 63;
  int n = blockIdx.x * 4 + w;
  const float* hr = h2f + (size_t)n * D_;
  float pl[4] = {0.f, 0.f, 0.f, 0.f};
  for (int d = l; d < D_; d += 64){
    float hv = hr[d];
    float4 wg = *(const float4*)&Wg[d * 4];
    pl[0] += hv * wg.x; pl[1] += hv * wg.y; pl[2] += hv * wg.z; pl[3] += hv * wg.w;
  }
  #pragma unroll
  for (int m = 1; m < 64; m <<= 1)
    #pragma unroll
    for (int g = 0; g < 4; g++) pl[g] += __shfl_xor(pl[g], m);
  float lg[4];
  #pragma unroll
  for (int g = 0; g < 4; g++) lg[g] = pl[g] + bg[g];
  int gi = 0; float gm = lg[0];
  #pragma unroll
  for (int g = 1; g < 4; g++) if (lg[g] > gm){ gm = lg[g]; gi = g; }
  float gs = 0.f;
  #pragma unroll
  for (int g = 0; g < 4; g++) gs += expf(lg[g] - gm);
  float pg = 1.f / gs;
  float e0 = 0.f, e1 = 0.f;
  for (int d = l; d < D_; d += 64){
    float hv = hr[d];
    float2 we = *(const float2*)&We[((size_t)gi * D_ + d) * 2];
    e0 += hv * we.x; e1 += hv * we.y;
  }
  #pragma unroll
  for (int m = 1; m < 64; m <<= 1){ e0 += __shfl_xor(e0, m); e1 += __shfl_xor(e1, m); }
  e0 += be[gi * 2]; e1 += be[gi * 2 + 1];
  int ei; float pe;
  if (e1 > e0){ ei = 1; pe = 1.f / (1.f + expf(e0 - e1)); }
  else        { ei = 0; pe = 1.f / (1.f + expf(e1 - e0)); }
  if (l == 0){
    flat[n] = gi * 2 + ei;
    pc[n] = pg * pe;
  }
}

// ---------------- single-block bucketing: counts, offsets, placement ----------------
__global__ __launch_bounds__(1024) void k_bucket(
    const int* __restrict__ flat, int* __restrict__ moeI, int* __restrict__ order){
  __shared__ int cnt[E_], off[E_], cur[E_];
  int t = threadIdx.x;
  if (t < E_){ cnt[t] = 0; cur[t] = 0; }
  __syncthreads();
  int n0 = t, n1 = t + 1024;
  int f0 = flat[n0], f1 = flat[n1];
  atomicAdd(&cnt[f0], 1);
  atomicAdd(&cnt[f1], 1);
  __syncthreads();
  if (t == 0){
    int s = 0;
    for (int e = 0; e < E_; e++){
      off[e] = s; moeI[16 + e] = s; moeI[e] = cnt[e]; s += cnt[e];
    }
  }
  __syncthreads();
  int p0 = atomicAdd(&cur[f0], 1);
  order[off[f0] + p0] = n0;
  int p1 = atomicAdd(&cur[f1], 1);
  order[off[f1] + p1] = n1;
}

// ------- pipelined grouped GEMM 1 (64x64, BK=64, swizzled ^row&7) -------
__global__ __launch_bounds__(256) void k_moe_gemm1(
    const u16* __restrict__ h2, const u16* __restrict__ W1t, const float* __restrict__ b1,
    const int* __restrict__ order, const int* __restrict__ moeI, u16* __restrict__ hid){
  int e = blockIdx.x, mt = blockIdx.y, nt = blockIdx.z;
  int cnt = moeI[e];
  if (mt * 64 >= cnt) return;
  int off = moeI[16 + e];
  __shared__ alignas(16) u16 As[2][64 * 64];
  __shared__ alignas(16) u16 Bs[2][64 * 64];
  int tid = threadIdx.x, w = tid >> 6, l = tid & 63;
  int wr = w >> 1, wc = w & 1;
  f32x4 acc[2][2];
  #pragma unroll
  for (int i = 0; i < 2; i++)
    #pragma unroll
    for (int j = 0; j < 2; j++) acc[i][j] = f32x4{0.f, 0.f, 0.f, 0.f};
  int r0 = w * 16 + (l >> 3);
  int sch = 8 * ((l & 7) ^ (l >> 3));
  int tokA0 = order[off + min(mt * 64 + r0, cnt - 1)];
  int tokA1 = order[off + min(mt * 64 + r0 + 8, cnt - 1)];
  const u16* gA0 = h2 + (size_t)tokA0 * D_ + sch;
  const u16* gA1 = h2 + (size_t)tokA1 * D_ + sch;
  const u16* gB0 = W1t + (size_t)e * HID_ * D_ + (size_t)(nt * 64 + r0) * D_ + sch;
  const u16* gB1 = gB0 + (size_t)8 * D_;
  int d0 = (w * 16) * 64, d1 = (w * 16 + 8) * 64;
  auto STAGE = [&](int buf, int k0){
    gload_lds16(gA0 + k0, &As[buf][d0]);
    gload_lds16(gA1 + k0, &As[buf][d1]);
    gload_lds16(gB0 + k0, &Bs[buf][d0]);
    gload_lds16(gB1 + k0, &Bs[buf][d1]);
  };
  STAGE(0, 0);
  __syncthreads();
  int c0 = (l >> 4) ^ (l & 7);
  int c1 = ((l >> 4) + 4) ^ (l & 7);
  const int nk = D_ / 64;
  for (int t = 0; t < nk; t++){
    int cur = t & 1;
    if (t + 1 < nk) STAGE(cur ^ 1, (t + 1) * 64);
    bf16x8 af[2][2], bfr[2][2];
    #pragma unroll
    for (int mi = 0; mi < 2; mi++){
      int rbase = (wr * 32 + mi * 16 + (l & 15)) * 64;
      af[mi][0] = *(const bf16x8*)&As[cur][rbase + 8 * c0];
      af[mi][1] = *(const bf16x8*)&As[cur][rbase + 8 * c1];
    }
    #pragma unroll
    for (int ni = 0; ni < 2; ni++){
      int rbase = (wc * 32 + ni * 16 + (l & 15)) * 64;
      bfr[ni][0] = *(const bf16x8*)&Bs[cur][rbase + 8 * c0];
      bfr[ni][1] = *(const bf16x8*)&Bs[cur][rbase + 8 * c1];
    }
    #pragma unroll
    for (int mi = 0; mi < 2; mi++)
      #pragma unroll
      for (int ni = 0; ni < 2; ni++){
        acc[mi][ni] = __builtin_amdgcn_mfma_f32_16x16x32_bf16(af[mi][0], bfr[ni][0], acc[mi][ni], 0, 0, 0);
        acc[mi][ni] = __builtin_amdgcn_mfma_f32_16x16x32_bf16(af[mi][1], bfr[ni][1], acc[mi][ni], 0, 0, 0);
      }
    __syncthreads();
  }
  int r4 = (l >> 4) * 4, cc = l & 15;
  #pragma unroll
  for (int mi = 0; mi < 2; mi++){
    #pragma unroll
    for (int ni = 0; ni < 2; ni++){
      int col = nt * 64 + wc * 32 + ni * 16 + cc;
      float bv = b1[e * HID_ + col];
      #pragma unroll
      for (int r = 0; r < 4; r++){
        int rowl = mt * 64 + wr * 32 + mi * 16 + r4 + r;
        if (rowl < cnt){
          float v = gelu_tanh(acc[mi][ni][r] + bv);
          hid[(size_t)(off + rowl) * HID_ + col] = f2bf(v);
        }
      }
    }
  }
}

// ------- pipelined grouped GEMM 2 (64x64, BK=64, swizzled) -------
__global__ __launch_bounds__(256) void k_moe_gemm2(
    const u16* __restrict__ hid, const u16* __restrict__ W2t, const float* __restrict__ b2,
    const int* __restrict__ order, const int* __restrict__ moeI,
    const float* __restrict__ pc, const float* __restrict__ x2, float* __restrict__ out){
  int e = blockIdx.x, mt = blockIdx.y, nt = blockIdx.z;
  int cnt = moeI[e];
  if (mt * 64 >= cnt) return;
  int off = moeI[16 + e];
  __shared__ alignas(16) u16 As[2][64 * 64];
  __shared__ alignas(16) u16 Bs[2][64 * 64];
  int tid = threadIdx.x, w = tid >> 6, l = tid & 63;
  int wr = w >> 1, wc = w & 1;
  f32x4 acc[2][2];
  #pragma unroll
  for (int i = 0; i < 2; i++)
    #pragma unroll
    for (int j = 0; j < 2; j++) acc[i][j] = f32x4{0.f, 0.f, 0.f, 0.f};
  int r0 = w * 16 + (l >> 3);
  int sch = 8 * ((l & 7) ^ (l >> 3));
  int ar0 = off + min(mt * 64 + r0, cnt - 1);
  int ar1 = off + min(mt * 64 + r0 + 8, cnt - 1);
  const u16* gA0 = hid + (size_t)ar0 * HID_ + sch;
  const u16* gA1 = hid + (size_t)ar1 * HID_ + sch;
  const u16* gB0 = W2t + (size_t)e * D_ * HID_ + (size_t)(nt * 64 + r0) * HID_ + sch;
  const u16* gB1 = gB0 + (size_t)8 * HID_;
  int d0 = (w * 16) * 64, d1 = (w * 16 + 8) * 64;
  auto STAGE = [&](int buf, int k0){
    gload_lds16(gA0 + k0, &As[buf][d0]);
    gload_lds16(gA1 + k0, &As[buf][d1]);
    gload_lds16(gB0 + k0, &Bs[buf][d0]);
    gload_lds16(gB1 + k0, &Bs[buf][d1]);
  };
  STAGE(0, 0);
  __syncthreads();
  int c0 = (l >> 4) ^ (l & 7);
  int c1 = ((l >> 4) + 4) ^ (l & 7);
  const int nk = HID_ / 64;
  for (int t = 0; t < nk; t++){
    int cur = t & 1;
    if (t + 1 < nk) STAGE(cur ^ 1, (t + 1) * 64);
    bf16x8 af[2][2], bfr[2][2];
    #pragma unroll
    for (int mi = 0; mi < 2; mi++){
      int rbase = (wr * 32 + mi * 16 + (l & 15)) * 64;
      af[mi][0] = *(const bf16x8*)&As[cur][rbase + 8 * c0];
      af[mi][1] = *(const bf16x8*)&As[cur][rbase + 8 * c1];
    }
    #pragma unroll
    for (int ni = 0; ni < 2; ni++){
      int rbase = (wc * 32 + ni * 16 + (l & 15)) * 64;
      bfr[ni][0] = *(const bf16x8*)&Bs[cur][rbase + 8 * c0];
      bfr[ni][1] = *(const bf16x8*)&Bs[cur][rbase + 8 * c1];
    }
    #pragma unroll
    for (int mi = 0; mi < 2; mi++)
      #pragma unroll
      for (int ni = 0; ni < 2; ni++){
        acc[mi][ni] = __builtin_amdgcn_mfma_f32_16x16x32_bf16(af[mi][0], bfr[ni][0], acc[mi][ni], 0, 0, 0);
        acc[mi][ni] = __builtin_amdgcn_mfma_f32_16x16x32_bf16(af[mi][1], bfr[ni][1], acc[mi][ni], 0, 0, 0);
      }
    __syncthreads();
  }
  int r4 = (l >> 4) * 4, cc = l & 15;
  #pragma unroll
  for (int mi = 0; mi < 2; mi++){
    #pragma unroll
    for (int r = 0; r < 4; r++){
      int rowl = mt * 64 + wr * 32 + mi * 16 + r4 + r;
      if (rowl < cnt){
        int tok = order[off + rowl];
        float pv = pc[tok];
        #pragma unroll
        for (int ni = 0; ni < 2; ni++){
          int col = nt * 64 + wc * 32 + ni * 16 + cc;
          float v = acc[mi][ni][r] + b2[e * D_ + col];
          out[(size_t)tok * D_ + col] = x2[(size_t)tok * D_ + col] + pv * v;
        }
      }
    }
  }
}

extern "C" void kernel_launch(void* const* d_in, const int* in_sizes, int n_in,
                              void* d_out, int out_size, void* d_ws, size_t ws_size,
                              hipStream_t stream){
  const float* x         = (const float*)d_in[0];
  const float* ln1_w     = (const float*)d_in[1];
  const float* ln1_b     = (const float*)d_in[2];
  const float* in_proj_w = (const float*)d_in[3];
  const float* in_proj_b = (const float*)d_in[4];
  const float* out_proj_w= (const float*)d_in[5];
  const float* out_proj_b= (const float*)d_in[6];
  const float* ln2_w     = (const float*)d_in[7];
  const float* ln2_b     = (const float*)d_in[8];
  const float* Wg        = (const float*)d_in[9];
  const float* bg        = (const float*)d_in[10];
  const float* We        = (const float*)d_in[11];
  const float* be        = (const float*)d_in[12];
  const float* W1        = (const float*)d_in[13];
  const float* b1        = (const float*)d_in[14];
  const float* W2        = (const float*)d_in[15];
  const float* b2        = (const float*)d_in[16];
  float* out = (float*)d_out;

  char* ws = (char*)d_ws;
  size_t off = 0;
  auto alloc = [&](size_t bytes) -> char* {
    char* p = ws + off;
    off += (bytes + 255) & ~(size_t)255;
    return p;
  };
  u16*   inpTh = (u16*)  alloc((size_t)3 * D_ * D_ * 2);  // 3538944 B
  u16*   inpTl = (u16*)  alloc((size_t)3 * D_ * D_ * 2);  // contiguous with inpTh
  u16*   outpTh= (u16*)  alloc((size_t)D_ * D_ * 2);
  u16*   outpTl= (u16*)  alloc((size_t)D_ * D_ * 2);
  u16*   W1t  = (u16*)  alloc((size_t)E_ * HID_ * D_ * 2);
  u16*   W2t  = (u16*)  alloc((size_t)E_ * D_ * HID_ * 2);
  u16*   qkvh = (u16*)  alloc((size_t)NTOK * 3 * D_ * 2); // 9.44 MB
  u16*   qkvl = (u16*)  alloc((size_t)NTOK * 3 * D_ * 2);
  u16*   h1h  = (u16*)  alloc((size_t)NTOK * D_ * 2);     // 3145728 B
  u16*   h1l  = (u16*)  alloc((size_t)NTOK * D_ * 2);     // contiguous with h1h
  u16*   vth  = (u16*)  alloc((size_t)B_ * NH_ * DH_ * S_ * 2);
  u16*   vtl  = (u16*)  alloc((size_t)B_ * NH_ * DH_ * S_ * 2);
  float* x2   = (float*)alloc((size_t)NTOK * D_ * 4);
  u16*   h2   = (u16*)  alloc((size_t)NTOK * D_ * 2);
  int*   flat = (int*)  alloc(NTOK * 4);
  float* pc   = (float*)alloc(NTOK * 4);
  int*   order= (int*)  alloc(NTOK * 4);
  int*   moeI = (int*)  alloc(32 * 4);
  // aliases (lifetimes disjoint, verified sequential):
  // attn partials: po0 over h1 (dead after QKV); po1+pm+pl over inpT (dead after QKV)
  float* po0  = (float*)h1h;                              // 384*64*64*4 = 6291456 <= 6291456+
  float* po1  = (float*)inpTh;                            // 6291456 <= 7077888
  float* pmArr= (float*)((char*)inpTh + 6291456);         // 2*384*64*4 = 196608
  float* plArr= (float*)((char*)inpTh + 6291456 + 196608);
  // attn merged output over qkv (dead after attn partials read)
  u16*   attnh= qkvh;
  u16*   attnl= qkvl;
  // h2f over qkvh (attnh dead after out-proj); hid over qkvl (attnl dead after out-proj)
  float* h2f  = (float*)qkvh;
  u16*   hid  = (u16*)qkvl;

  // fused weight prep
  k_prep<<<dim3(20736), dim3(256), 0, stream>>>(
      in_proj_w, out_proj_w, W1, W2, inpTh, inpTl, outpTh, outpTl, W1t, W2t);
  // LN1 (split output)
  k_layernorm<<<dim3(NTOK), dim3(256), 0, stream>>>(x, ln1_w, ln1_b, h1h, h1l, (float*)nullptr);
  // QKV (split GEMM -> split output)
  k_gemm3<0><<<dim3(NTOK / 64, 3 * D_ / 64), dim3(256), 0, stream>>>(
      h1h, h1l, inpTh, inpTl, in_proj_b, nullptr, qkvh, qkvl, nullptr, NTOK, 3 * D_, D_);
  // V transpose
  k_transpose_v<<<dim3(DH_ / 32, S_ / 32, B_ * NH_), dim3(32, 8), 0, stream>>>(qkvh, qkvl, vth, vtl);
  // attention split-K partials (bh-major grid for XCD L2 locality)
  k_attn3<<<dim3(B_ * NH_, S_ / 64, 2), dim3(256), 0, stream>>>(
      qkvh, qkvl, vth, vtl, po0, po1, pmArr, plArr);
  // merge halves -> split bf16 attn (into qkv region)
  k_attn_merge<<<dim3(B_ * NH_, S_ / 64), dim3(256), 0, stream>>>(
      po0, po1, pmArr, plArr, attnh, attnl);
  // out-proj + residual -> x2 (f32)
  k_gemm3<1><<<dim3(NTOK / 64, D_ / 64), dim3(256), 0, stream>>>(
      attnh, attnl, outpTh, outpTl, out_proj_b, x, nullptr, nullptr, x2, NTOK, D_, D_);
  // LN2: bf16 hi for MoE + f32 for router
  k_layernorm<<<dim3(NTOK), dim3(256), 0, stream>>>(x2, ln2_w, ln2_b, h2, (u16*)nullptr, h2f);
  // router + bucketing
  k_router<<<dim3(NTOK / 4), dim3(256), 0, stream>>>(h2f, Wg, bg, We, be, flat, pc);
  k_bucket<<<dim3(1), dim3(1024), 0, stream>>>(flat, moeI, order);
  // grouped expert GEMMs (e = blockIdx.x -> XCD pin)
  k_moe_gemm1<<<dim3(E_, NTOK / 64, HID_ / 64), dim3(256), 0, stream>>>(h2, W1t, b1, order, moeI, hid);
  k_moe_gemm2<<<dim3(E_, NTOK / 64, D_ / 64), dim3(256), 0, stream>>>(hid, W2t, b2, order, moeI, pc, x2, out);
}

// Round 7
// 207.071 us; speedup vs baseline: 1.7017x; 1.0503x over previous
//
#include <hip/hip_runtime.h>
#include <stdint.h>

#define B_ 2
#define S_ 1024
#define D_ 768
#define NH_ 12
#define DH_ 64
#define HID_ 1536
#define G_ 4
#define EPG_ 2
#define E_ 8
#define NTOK (B_*S_)
#define NGRP (B_*NH_*16)   // 384 (bh x qb) groups

typedef unsigned short u16;
typedef unsigned int u32;
typedef __bf16 bf16x8 __attribute__((ext_vector_type(8)));
typedef float f32x4 __attribute__((ext_vector_type(4)));
typedef u16 u16x4 __attribute__((ext_vector_type(4)));
typedef u32 u32x4 __attribute__((ext_vector_type(4)));

struct BfPair { u16 hi, lo; };

__device__ __forceinline__ u16 f2bf(float f){
  unsigned u = __builtin_bit_cast(unsigned, f);
  u += 0x7FFFu + ((u >> 16) & 1u);
  return (u16)(u >> 16);
}
__device__ __forceinline__ float bf2f(u16 h){
  unsigned u = ((unsigned)h) << 16;
  return __builtin_bit_cast(float, u);
}
__device__ __forceinline__ BfPair split_bf(float v){
  BfPair p;
  p.hi = f2bf(v);
  p.lo = f2bf(v - bf2f(p.hi));
  return p;
}
__device__ __forceinline__ float gelu_tanh(float x){
  float t = 0.7978845608028654f * (x + 0.044715f * x * x * x);
  float e = __expf(2.f * t);
  float th = 1.f - 2.f / (e + 1.f);
  return 0.5f * x * (1.f + th);
}
__device__ __forceinline__ void gload_lds16(const void* g, void* l){
  __builtin_amdgcn_global_load_lds(
      (const __attribute__((address_space(1))) void*)g,
      (__attribute__((address_space(3))) void*)l, 16, 0, 0);
}

// ---------------- fused weight prep: converts + transposes in one kernel ----------------
__global__ __launch_bounds__(256) void k_prep(
    const float* __restrict__ in_proj_w, const float* __restrict__ out_proj_w,
    const float* __restrict__ W1, const float* __restrict__ W2,
    u16* __restrict__ inpTh, u16* __restrict__ inpTl,
    u16* __restrict__ outpTh, u16* __restrict__ outpTl,
    u16* __restrict__ W1t, u16* __restrict__ W2t){
  __shared__ float tile[32][33];
  int bid = blockIdx.x, t = threadIdx.x;
  if (bid < 2304){
    const float* src; u16 *dh, *dl; int i;
    if (bid < 1728){ src = in_proj_w; dh = inpTh; dl = inpTl; i = bid * 256 + t; }
    else           { src = out_proj_w; dh = outpTh; dl = outpTl; i = (bid - 1728) * 256 + t; }
    float4 v = ((const float4*)src)[i];
    u16x4 oh, ol;
    BfPair p0 = split_bf(v.x), p1 = split_bf(v.y), p2 = split_bf(v.z), p3 = split_bf(v.w);
    oh.x = p0.hi; ol.x = p0.lo; oh.y = p1.hi; ol.y = p1.lo;
    oh.z = p2.hi; ol.z = p2.lo; oh.w = p3.hi; ol.w = p3.lo;
    ((u16x4*)dh)[i] = oh;
    ((u16x4*)dl)[i] = ol;
  } else {
    const float* src; u16* dst; int R, C, cx, cy, e;
    if (bid < 11520){
      int r = bid - 2304; e = r / 1152; r %= 1152;
      R = D_; C = HID_; cx = r % 48; cy = r / 48;
      src = W1; dst = W1t;
    } else {
      int r = bid - 11520; e = r / 1152; r %= 1152;
      R = HID_; C = D_; cx = r % 24; cy = r / 24;
      src = W2; dst = W2t;
    }
    const float* s = src + (size_t)e * R * C;
    u16* d = dst + (size_t)e * R * C;
    int c0 = cx * 32, r0 = cy * 32;
    int tx = t & 31, ty = t >> 5;
    #pragma unroll
    for (int i = 0; i < 32; i += 8)
      tile[ty + i][tx] = s[(size_t)(r0 + ty + i) * C + c0 + tx];
    __syncthreads();
    #pragma unroll
    for (int i = 0; i < 32; i += 8)
      d[(size_t)(c0 + ty + i) * R + r0 + tx] = f2bf(tile[tx][ty + i]);
  }
}

// ---------------- V transpose: qkv hi/lo [N][2304] -> vt hi/lo [BH][64][1024] ----------
__global__ void k_transpose_v(const u16* __restrict__ qh, const u16* __restrict__ ql,
                              u16* __restrict__ vth, u16* __restrict__ vtl){
  __shared__ u16 th[32][34], tl[32][34];
  int bh = blockIdx.z, b = bh / NH_, h = bh % NH_;
  int d0 = blockIdx.x * 32, s0 = blockIdx.y * 32;
  #pragma unroll
  for (int i = 0; i < 32; i += 8){
    size_t src = (size_t)(b * S_ + s0 + threadIdx.y + i) * (3 * D_) + 2 * D_ + h * DH_ + d0 + threadIdx.x;
    th[threadIdx.y + i][threadIdx.x] = qh[src];
    tl[threadIdx.y + i][threadIdx.x] = ql[src];
  }
  __syncthreads();
  #pragma unroll
  for (int i = 0; i < 32; i += 8){
    size_t dst = ((size_t)bh * DH_ + d0 + threadIdx.y + i) * S_ + s0 + threadIdx.x;
    vth[dst] = th[threadIdx.x][threadIdx.y + i];
    vtl[dst] = tl[threadIdx.x][threadIdx.y + i];
  }
}

// ---------------- layernorm: f32 in -> bf16 hi (+lo) (+f32) ----------------
__global__ __launch_bounds__(256) void k_layernorm(
    const float* __restrict__ x, const float* __restrict__ w, const float* __restrict__ b,
    u16* __restrict__ oh, u16* __restrict__ ol, float* __restrict__ of){
  int row = blockIdx.x;
  const float* xr = x + (size_t)row * D_;
  int t = threadIdx.x;
  float v0 = xr[t], v1 = xr[t + 256], v2 = xr[t + 512];
  float s = v0 + v1 + v2;
  float sq = v0 * v0 + v1 * v1 + v2 * v2;
  #pragma unroll
  for (int m = 1; m < 64; m <<= 1){ s += __shfl_xor(s, m); sq += __shfl_xor(sq, m); }
  __shared__ float ls[4], lq[4];
  int wid = t >> 6;
  if ((t & 63) == 0){ ls[wid] = s; lq[wid] = sq; }
  __syncthreads();
  s = ls[0] + ls[1] + ls[2] + ls[3];
  sq = lq[0] + lq[1] + lq[2] + lq[3];
  float mean = s * (1.f / D_);
  float var = sq * (1.f / D_) - mean * mean;
  float rstd = rsqrtf(var + 1e-5f);
  #pragma unroll
  for (int i = 0; i < 3; i++){
    int dcol = t + i * 256;
    float v = (i == 0 ? v0 : (i == 1 ? v1 : v2));
    float y = (v - mean) * rstd * w[dcol] + b[dcol];
    BfPair p = split_bf(y);
    oh[(size_t)row * D_ + dcol] = p.hi;
    if (ol) ol[(size_t)row * D_ + dcol] = p.lo;
    if (of) of[(size_t)row * D_ + dcol] = y;
  }
}

// ------- pipelined split-precision GEMM 64x64 (BK=32, swizzled ^row&3) -------
template<int EPI>
__global__ __launch_bounds__(256) void k_gemm3(
    const u16* __restrict__ Ah, const u16* __restrict__ Al,
    const u16* __restrict__ Bh, const u16* __restrict__ Bl,
    const float* __restrict__ bias, const float* __restrict__ resid,
    u16* __restrict__ outh, u16* __restrict__ outl, float* __restrict__ outf,
    int M, int N, int K){
  __shared__ alignas(16) u16 Ash[2][64 * 32];
  __shared__ alignas(16) u16 Asl[2][64 * 32];
  __shared__ alignas(16) u16 Bsh[2][64 * 32];
  __shared__ alignas(16) u16 Bsl[2][64 * 32];
  int m0 = blockIdx.x * 64, n0 = blockIdx.y * 64;
  int tid = threadIdx.x, w = tid >> 6, l = tid & 63;
  int wr = w >> 1, wc = w & 1;
  f32x4 acc[2][2];
  #pragma unroll
  for (int i = 0; i < 2; i++)
    #pragma unroll
    for (int j = 0; j < 2; j++) acc[i][j] = f32x4{0.f, 0.f, 0.f, 0.f};
  int srow = w * 16 + (l >> 2);
  int scol = 8 * ((l & 3) ^ ((l >> 2) & 3));
  const u16* gAh = Ah + (size_t)(m0 + srow) * K + scol;
  const u16* gAl = Al + (size_t)(m0 + srow) * K + scol;
  const u16* gBh = Bh + (size_t)(n0 + srow) * K + scol;
  const u16* gBl = Bl + (size_t)(n0 + srow) * K + scol;
  int dOff = (w * 16) * 32;
  auto STAGE = [&](int buf, int k0){
    gload_lds16(gAh + k0, &Ash[buf][dOff]);
    gload_lds16(gAl + k0, &Asl[buf][dOff]);
    gload_lds16(gBh + k0, &Bsh[buf][dOff]);
    gload_lds16(gBl + k0, &Bsl[buf][dOff]);
  };
  STAGE(0, 0);
  __syncthreads();
  int nk = K / 32;
  int ca = (l >> 4) ^ (l & 3);
  int ai = (wr * 32 + (l & 15)) * 32 + 8 * ca;
  int bi = (wc * 32 + (l & 15)) * 32 + 8 * ca;
  for (int t = 0; t < nk; t++){
    int cur = t & 1;
    if (t + 1 < nk) STAGE(cur ^ 1, (t + 1) * 32);
    bf16x8 afh[2], afl[2], bfh[2], bfl[2];
    #pragma unroll
    for (int mi = 0; mi < 2; mi++){
      afh[mi] = *(const bf16x8*)&Ash[cur][ai + mi * 16 * 32];
      afl[mi] = *(const bf16x8*)&Asl[cur][ai + mi * 16 * 32];
    }
    #pragma unroll
    for (int ni = 0; ni < 2; ni++){
      bfh[ni] = *(const bf16x8*)&Bsh[cur][bi + ni * 16 * 32];
      bfl[ni] = *(const bf16x8*)&Bsl[cur][bi + ni * 16 * 32];
    }
    #pragma unroll
    for (int mi = 0; mi < 2; mi++)
      #pragma unroll
      for (int ni = 0; ni < 2; ni++){
        acc[mi][ni] = __builtin_amdgcn_mfma_f32_16x16x32_bf16(afh[mi], bfh[ni], acc[mi][ni], 0, 0, 0);
        acc[mi][ni] = __builtin_amdgcn_mfma_f32_16x16x32_bf16(afh[mi], bfl[ni], acc[mi][ni], 0, 0, 0);
        acc[mi][ni] = __builtin_amdgcn_mfma_f32_16x16x32_bf16(afl[mi], bfh[ni], acc[mi][ni], 0, 0, 0);
      }
    __syncthreads();
  }
  int r4 = (l >> 4) * 4, cc = l & 15;
  #pragma unroll
  for (int mi = 0; mi < 2; mi++){
    #pragma unroll
    for (int ni = 0; ni < 2; ni++){
      int col = n0 + wc * 32 + ni * 16 + cc;
      float bv = bias ? bias[col] : 0.f;
      #pragma unroll
      for (int r = 0; r < 4; r++){
        int row = m0 + wr * 32 + mi * 16 + r4 + r;
        float v = acc[mi][ni][r] + bv;
        if (EPI == 0){
          BfPair p = split_bf(v);
          outh[(size_t)row * N + col] = p.hi;
          outl[(size_t)row * N + col] = p.lo;
        } else {
          outf[(size_t)row * N + col] = v + resid[(size_t)row * N + col];
        }
      }
    }
  }
}

// ------- split-precision flash attention, split-K x2, KVBLK=32, swapped-QK in-reg softmax -------
// grid (bh=24, qb=16, ks=2)
__global__ __launch_bounds__(256) void k_attn3(
    const u16* __restrict__ qkvh, const u16* __restrict__ qkvl,
    const u16* __restrict__ vth, const u16* __restrict__ vtl,
    float* __restrict__ po0, float* __restrict__ po1,
    float* __restrict__ pm, float* __restrict__ plsum){
  __shared__ alignas(16) u16 Ksh[2][32 * 64];
  __shared__ alignas(16) u16 Ksl[2][32 * 64];
  __shared__ alignas(16) u16 Vsh[2][64 * 32];
  __shared__ alignas(16) u16 Vsl[2][64 * 32];
  int bh = blockIdx.x, qb = blockIdx.y, ks = blockIdx.z;
  int b = bh / NH_, h = bh % NH_;
  int g = bh * 16 + qb;
  int tid = threadIdx.x, w = tid >> 6, l = tid & 63;
  int q0 = qb * 64 + w * 16;
  const int RS = 3 * D_;
  size_t qoff = (size_t)(b * S_ + q0 + (l & 15)) * RS + h * DH_ + 8 * (l >> 4);
  bf16x8 aqh[2], aql[2];
  aqh[0] = *(const bf16x8*)(qkvh + qoff); aqh[1] = *(const bf16x8*)(qkvh + qoff + 32);
  aql[0] = *(const bf16x8*)(qkvl + qoff); aql[1] = *(const bf16x8*)(qkvl + qoff + 32);
  f32x4 oacc[4];
  #pragma unroll
  for (int i = 0; i < 4; i++) oacc[i] = f32x4{0.f, 0.f, 0.f, 0.f};
  float mrun = -1e30f, lrun = 0.f;   // per-lane softmax state for q = l&15

  size_t koff = (size_t)(b * S_ + w * 8 + (l >> 3)) * RS + D_ + h * DH_ + 8 * ((l & 7) ^ (l >> 3));
  const u16* Kgh = qkvh + koff;
  const u16* Kgl = qkvl + koff;
  size_t voff = ((size_t)bh * DH_ + w * 16 + (l >> 2)) * S_ + 8 * ((l & 3) ^ ((l >> 2) & 3));
  const u16* Vgh = vth + voff;
  const u16* Vgl = vtl + voff;
  int wdst = w * 512;

  auto STAGE = [&](int buf, int akt){
    gload_lds16(Kgh + (size_t)(akt * 32) * RS, &Ksh[buf][wdst]);
    gload_lds16(Kgl + (size_t)(akt * 32) * RS, &Ksl[buf][wdst]);
    gload_lds16(Vgh + akt * 32, &Vsh[buf][wdst]);
    gload_lds16(Vgl + akt * 32, &Vsl[buf][wdst]);
  };
  int kt0 = ks * 16;
  STAGE(0, kt0);
  __syncthreads();

  int ck0 = (l >> 4) ^ (l & 7);
  int ck1 = ck0 ^ 4;
  int cv = (l >> 4) ^ (l & 3);
  // P-exchange source lanes (build PV A-fragment from S^T registers)
  int s1 = (l & 15) | ((l & 16) << 1);  // b or b+32
  int s2 = s1 + 16;
  bool up = (l & 32) != 0;

  for (int kt = 0; kt < 16; kt++){
    int cur = kt & 1;
    if (kt + 1 < 16) STAGE(cur ^ 1, kt0 + kt + 1);
    // swapped QK^T: S^T[k][q], lane holds q=l&15, k = 4c+r (st0) / 16+4c+r (st1), c=l>>4
    f32x4 st[2];
    #pragma unroll
    for (int nt = 0; nt < 2; nt++){
      int rbase = (nt * 16 + (l & 15)) * 64;
      bf16x8 kh0 = *(const bf16x8*)&Ksh[cur][rbase + 8 * ck0];
      bf16x8 kh1 = *(const bf16x8*)&Ksh[cur][rbase + 8 * ck1];
      bf16x8 kl0 = *(const bf16x8*)&Ksl[cur][rbase + 8 * ck0];
      bf16x8 kl1 = *(const bf16x8*)&Ksl[cur][rbase + 8 * ck1];
      f32x4 c = f32x4{0.f, 0.f, 0.f, 0.f};
      c = __builtin_amdgcn_mfma_f32_16x16x32_bf16(kh0, aqh[0], c, 0, 0, 0);
      c = __builtin_amdgcn_mfma_f32_16x16x32_bf16(kh1, aqh[1], c, 0, 0, 0);
      c = __builtin_amdgcn_mfma_f32_16x16x32_bf16(kh0, aql[0], c, 0, 0, 0);
      c = __builtin_amdgcn_mfma_f32_16x16x32_bf16(kh1, aql[1], c, 0, 0, 0);
      c = __builtin_amdgcn_mfma_f32_16x16x32_bf16(kl0, aqh[0], c, 0, 0, 0);
      c = __builtin_amdgcn_mfma_f32_16x16x32_bf16(kl1, aqh[1], c, 0, 0, 0);
      st[nt] = c;
    }
    // in-register online softmax (row = q = l&15; 8 k-vals/lane, 4 lanes per q)
    float mx = fmaxf(fmaxf(fmaxf(st[0][0], st[0][1]), fmaxf(st[0][2], st[0][3])),
                     fmaxf(fmaxf(st[1][0], st[1][1]), fmaxf(st[1][2], st[1][3])));
    mx = fmaxf(mx, __shfl_xor(mx, 16));
    mx = fmaxf(mx, __shfl_xor(mx, 32));
    mx *= 0.125f;
    float mnew = fmaxf(mrun, mx);
    float alpha = __expf(mrun - mnew);
    mrun = mnew;
    float p[8]; float sum = 0.f;
    #pragma unroll
    for (int j = 0; j < 8; j++){
      p[j] = __expf(st[j >> 2][j & 3] * 0.125f - mnew);
      sum += p[j];
    }
    sum += __shfl_xor(sum, 16);
    sum += __shfl_xor(sum, 32);
    lrun = lrun * alpha + sum;
    // split to bf16 hi/lo, pack, exchange into PV A-fragment (k = 8c..8c+7 per lane)
    u32 pkh[4], pkl[4];
    #pragma unroll
    for (int i = 0; i < 4; i++){
      BfPair a = split_bf(p[2 * i]), bb = split_bf(p[2 * i + 1]);
      pkh[i] = (u32)a.hi | ((u32)bb.hi << 16);
      pkl[i] = (u32)a.lo | ((u32)bb.lo << 16);
    }
    u32 ah0 = __shfl((int)pkh[0], s1), ah1 = __shfl((int)pkh[1], s1);
    u32 ah2 = __shfl((int)pkh[2], s1), ah3 = __shfl((int)pkh[3], s1);
    u32 bh0 = __shfl((int)pkh[0], s2), bh1 = __shfl((int)pkh[1], s2);
    u32 bh2 = __shfl((int)pkh[2], s2), bh3 = __shfl((int)pkh[3], s2);
    u32 al0 = __shfl((int)pkl[0], s1), al1 = __shfl((int)pkl[1], s1);
    u32 al2 = __shfl((int)pkl[2], s1), al3 = __shfl((int)pkl[3], s1);
    u32 bl0 = __shfl((int)pkl[0], s2), bl1 = __shfl((int)pkl[1], s2);
    u32 bl2 = __shfl((int)pkl[2], s2), bl3 = __shfl((int)pkl[3], s2);
    u32x4 fh, fl;
    fh.x = up ? ah2 : ah0; fh.y = up ? ah3 : ah1; fh.z = up ? bh2 : bh0; fh.w = up ? bh3 : bh1;
    fl.x = up ? al2 : al0; fl.y = up ? al3 : al1; fl.z = up ? bl2 : bl0; fl.w = up ? bl3 : bl1;
    bf16x8 pa_h = __builtin_bit_cast(bf16x8, fh);
    bf16x8 pa_l = __builtin_bit_cast(bf16x8, fl);
    // rescale accumulator (alpha redistributed to acc row layout q=(l>>4)*4+r)
    #pragma unroll
    for (int r = 0; r < 4; r++){
      float ar = __shfl(alpha, (l & 48) | (((l >> 4) << 2) + r));
      oacc[0][r] *= ar; oacc[1][r] *= ar; oacc[2][r] *= ar; oacc[3][r] *= ar;
    }
    // PV
    #pragma unroll
    for (int dt = 0; dt < 4; dt++){
      int vb = (dt * 16 + (l & 15)) * 32 + 8 * cv;
      bf16x8 bvh = *(const bf16x8*)&Vsh[cur][vb];
      bf16x8 bvl = *(const bf16x8*)&Vsl[cur][vb];
      oacc[dt] = __builtin_amdgcn_mfma_f32_16x16x32_bf16(pa_h, bvh, oacc[dt], 0, 0, 0);
      oacc[dt] = __builtin_amdgcn_mfma_f32_16x16x32_bf16(pa_h, bvl, oacc[dt], 0, 0, 0);
      oacc[dt] = __builtin_amdgcn_mfma_f32_16x16x32_bf16(pa_l, bvh, oacc[dt], 0, 0, 0);
    }
    __syncthreads();
  }
  // partial epilogue: unnormalized O + m + l
  float* po = ks ? po1 : po0;
  #pragma unroll
  for (int dt = 0; dt < 4; dt++)
    #pragma unroll
    for (int r = 0; r < 4; r++){
      int qloc = w * 16 + (l >> 4) * 4 + r;
      int d = dt * 16 + (l & 15);
      po[((size_t)(g * 64 + qloc)) * 64 + d] = oacc[dt][r];
    }
  if (l < 16){
    pm[(ks * NGRP + g) * 64 + w * 16 + l] = mrun;
    plsum[(ks * NGRP + g) * 64 + w * 16 + l] = lrun;
  }
}

// ---------------- attn split-K merge -> split bf16 attn output ----------------
__global__ __launch_bounds__(256) void k_attn_merge(
    const float* __restrict__ po0, const float* __restrict__ po1,
    const float* __restrict__ pm, const float* __restrict__ plsum,
    u16* __restrict__ oh, u16* __restrict__ ol){
  int bh = blockIdx.x, qb = blockIdx.y;
  int b = bh / NH_, h = bh % NH_;
  int g = bh * 16 + qb;
  int t = threadIdx.x;
  int q = t >> 2, d0 = (t & 3) * 16;
  float m0 = pm[g * 64 + q],      m1 = pm[NGRP * 64 + g * 64 + q];
  float l0 = plsum[g * 64 + q],   l1 = plsum[NGRP * 64 + g * 64 + q];
  float M = fmaxf(m0, m1);
  float a0 = __expf(m0 - M), a1 = __expf(m1 - M);
  float rcp = 1.f / (l0 * a0 + l1 * a1);
  size_t base = ((size_t)(g * 64 + q)) * 64 + d0;
  size_t orow = (size_t)(b * S_ + qb * 64 + q) * D_ + h * DH_ + d0;
  #pragma unroll
  for (int j = 0; j < 16; j++){
    float v = (po0[base + j] * a0 + po1[base + j] * a1) * rcp;
    BfPair p = split_bf(v);
    oh[orow + j] = p.hi;
    ol[orow + j] = p.lo;
  }
}

// ---------------- router (f32, no atomics) ----------------
__global__ __launch_bounds__(256) void k_router(
    const float* __restrict__ h2f, const float* __restrict__ Wg, const float* __restrict__ bg,
    const float* __restrict__ We, const float* __restrict__ be,
    int* __restrict__ flat, float* __restrict__ pc){
  int w = threadIdx.x >> 6, l = threadIdx.x & 63;
  int n = blockIdx.x * 4 + w;
  const float* hr = h2f + (size_t)n * D_;
  float pl[4] = {0.f, 0.f, 0.f, 0.f};
  for (int d = l; d < D_; d += 64){
    float hv = hr[d];
    float4 wg = *(const float4*)&Wg[d * 4];
    pl[0] += hv * wg.x; pl[1] += hv * wg.y; pl[2] += hv * wg.z; pl[3] += hv * wg.w;
  }
  #pragma unroll
  for (int m = 1; m < 64; m <<= 1)
    #pragma unroll
    for (int g = 0; g < 4; g++) pl[g] += __shfl_xor(pl[g], m);
  float lg[4];
  #pragma unroll
  for (int g = 0; g < 4; g++) lg[g] = pl[g] + bg[g];
  int gi = 0; float gm = lg[0];
  #pragma unroll
  for (int g = 1; g < 4; g++) if (lg[g] > gm){ gm = lg[g]; gi = g; }
  float gs = 0.f;
  #pragma unroll
  for (int g = 0; g < 4; g++) gs += expf(lg[g] - gm);
  float pg = 1.f / gs;
  float e0 = 0.f, e1 = 0.f;
  for (int d = l; d < D_; d += 64){
    float hv = hr[d];
    float2 we = *(const float2*)&We[((size_t)gi * D_ + d) * 2];
    e0 += hv * we.x; e1 += hv * we.y;
  }
  #pragma unroll
  for (int m = 1; m < 64; m <<= 1){ e0 += __shfl_xor(e0, m); e1 += __shfl_xor(e1, m); }
  e0 += be[gi * 2]; e1 += be[gi * 2 + 1];
  int ei; float pe;
  if (e1 > e0){ ei = 1; pe = 1.f / (1.f + expf(e0 - e1)); }
  else        { ei = 0; pe = 1.f / (1.f + expf(e1 - e0)); }
  if (l == 0){
    flat[n] = gi * 2 + ei;
    pc[n] = pg * pe;
  }
}

// ---------------- single-block bucketing ----------------
__global__ __launch_bounds__(1024) void k_bucket(
    const int* __restrict__ flat, int* __restrict__ moeI, int* __restrict__ order){
  __shared__ int cnt[E_], off[E_], cur[E_];
  int t = threadIdx.x;
  if (t < E_){ cnt[t] = 0; cur[t] = 0; }
  __syncthreads();
  int n0 = t, n1 = t + 1024;
  int f0 = flat[n0], f1 = flat[n1];
  atomicAdd(&cnt[f0], 1);
  atomicAdd(&cnt[f1], 1);
  __syncthreads();
  if (t == 0){
    int s = 0;
    for (int e = 0; e < E_; e++){
      off[e] = s; moeI[16 + e] = s; moeI[e] = cnt[e]; s += cnt[e];
    }
  }
  __syncthreads();
  int p0 = atomicAdd(&cur[f0], 1);
  order[off[f0] + p0] = n0;
  int p1 = atomicAdd(&cur[f1], 1);
  order[off[f1] + p1] = n1;
}

// ------- pipelined grouped GEMM 1 (64x64, BK=64, swizzled ^row&7) -------
__global__ __launch_bounds__(256) void k_moe_gemm1(
    const u16* __restrict__ h2, const u16* __restrict__ W1t, const float* __restrict__ b1,
    const int* __restrict__ order, const int* __restrict__ moeI, u16* __restrict__ hid){
  int e = blockIdx.x, mt = blockIdx.y, nt = blockIdx.z;
  int cnt = moeI[e];
  if (mt * 64 >= cnt) return;
  int off = moeI[16 + e];
  __shared__ alignas(16) u16 As[2][64 * 64];
  __shared__ alignas(16) u16 Bs[2][64 * 64];
  int tid = threadIdx.x, w = tid >> 6, l = tid & 63;
  int wr = w >> 1, wc = w & 1;
  f32x4 acc[2][2];
  #pragma unroll
  for (int i = 0; i < 2; i++)
    #pragma unroll
    for (int j = 0; j < 2; j++) acc[i][j] = f32x4{0.f, 0.f, 0.f, 0.f};
  int r0 = w * 16 + (l >> 3);
  int sch = 8 * ((l & 7) ^ (l >> 3));
  int tokA0 = order[off + min(mt * 64 + r0, cnt - 1)];
  int tokA1 = order[off + min(mt * 64 + r0 + 8, cnt - 1)];
  const u16* gA0 = h2 + (size_t)tokA0 * D_ + sch;
  const u16* gA1 = h2 + (size_t)tokA1 * D_ + sch;
  const u16* gB0 = W1t + (size_t)e * HID_ * D_ + (size_t)(nt * 64 + r0) * D_ + sch;
  const u16* gB1 = gB0 + (size_t)8 * D_;
  int d0 = (w * 16) * 64, d1 = (w * 16 + 8) * 64;
  auto STAGE = [&](int buf, int k0){
    gload_lds16(gA0 + k0, &As[buf][d0]);
    gload_lds16(gA1 + k0, &As[buf][d1]);
    gload_lds16(gB0 + k0, &Bs[buf][d0]);
    gload_lds16(gB1 + k0, &Bs[buf][d1]);
  };
  STAGE(0, 0);
  __syncthreads();
  int c0 = (l >> 4) ^ (l & 7);
  int c1 = ((l >> 4) + 4) ^ (l & 7);
  const int nk = D_ / 64;
  for (int t = 0; t < nk; t++){
    int cur = t & 1;
    if (t + 1 < nk) STAGE(cur ^ 1, (t + 1) * 64);
    bf16x8 af[2][2], bfr[2][2];
    #pragma unroll
    for (int mi = 0; mi < 2; mi++){
      int rbase = (wr * 32 + mi * 16 + (l & 15)) * 64;
      af[mi][0] = *(const bf16x8*)&As[cur][rbase + 8 * c0];
      af[mi][1] = *(const bf16x8*)&As[cur][rbase + 8 * c1];
    }
    #pragma unroll
    for (int ni = 0; ni < 2; ni++){
      int rbase = (wc * 32 + ni * 16 + (l & 15)) * 64;
      bfr[ni][0] = *(const bf16x8*)&Bs[cur][rbase + 8 * c0];
      bfr[ni][1] = *(const bf16x8*)&Bs[cur][rbase + 8 * c1];
    }
    #pragma unroll
    for (int mi = 0; mi < 2; mi++)
      #pragma unroll
      for (int ni = 0; ni < 2; ni++){
        acc[mi][ni] = __builtin_amdgcn_mfma_f32_16x16x32_bf16(af[mi][0], bfr[ni][0], acc[mi][ni], 0, 0, 0);
        acc[mi][ni] = __builtin_amdgcn_mfma_f32_16x16x32_bf16(af[mi][1], bfr[ni][1], acc[mi][ni], 0, 0, 0);
      }
    __syncthreads();
  }
  int r4 = (l >> 4) * 4, cc = l & 15;
  #pragma unroll
  for (int mi = 0; mi < 2; mi++){
    #pragma unroll
    for (int ni = 0; ni < 2; ni++){
      int col = nt * 64 + wc * 32 + ni * 16 + cc;
      float bv = b1[e * HID_ + col];
      #pragma unroll
      for (int r = 0; r < 4; r++){
        int rowl = mt * 64 + wr * 32 + mi * 16 + r4 + r;
        if (rowl < cnt){
          float v = gelu_tanh(acc[mi][ni][r] + bv);
          hid[(size_t)(off + rowl) * HID_ + col] = f2bf(v);
        }
      }
    }
  }
}

// ------- pipelined grouped GEMM 2 (64x64, BK=64, swizzled) -------
__global__ __launch_bounds__(256) void k_moe_gemm2(
    const u16* __restrict__ hid, const u16* __restrict__ W2t, const float* __restrict__ b2,
    const int* __restrict__ order, const int* __restrict__ moeI,
    const float* __restrict__ pc, const float* __restrict__ x2, float* __restrict__ out){
  int e = blockIdx.x, mt = blockIdx.y, nt = blockIdx.z;
  int cnt = moeI[e];
  if (mt * 64 >= cnt) return;
  int off = moeI[16 + e];
  __shared__ alignas(16) u16 As[2][64 * 64];
  __shared__ alignas(16) u16 Bs[2][64 * 64];
  int tid = threadIdx.x, w = tid >> 6, l = tid & 63;
  int wr = w >> 1, wc = w & 1;
  f32x4 acc[2][2];
  #pragma unroll
  for (int i = 0; i < 2; i++)
    #pragma unroll
    for (int j = 0; j < 2; j++) acc[i][j] = f32x4{0.f, 0.f, 0.f, 0.f};
  int r0 = w * 16 + (l >> 3);
  int sch = 8 * ((l & 7) ^ (l >> 3));
  int ar0 = off + min(mt * 64 + r0, cnt - 1);
  int ar1 = off + min(mt * 64 + r0 + 8, cnt - 1);
  const u16* gA0 = hid + (size_t)ar0 * HID_ + sch;
  const u16* gA1 = hid + (size_t)ar1 * HID_ + sch;
  const u16* gB0 = W2t + (size_t)e * D_ * HID_ + (size_t)(nt * 64 + r0) * HID_ + sch;
  const u16* gB1 = gB0 + (size_t)8 * HID_;
  int d0 = (w * 16) * 64, d1 = (w * 16 + 8) * 64;
  auto STAGE = [&](int buf, int k0){
    gload_lds16(gA0 + k0, &As[buf][d0]);
    gload_lds16(gA1 + k0, &As[buf][d1]);
    gload_lds16(gB0 + k0, &Bs[buf][d0]);
    gload_lds16(gB1 + k0, &Bs[buf][d1]);
  };
  STAGE(0, 0);
  __syncthreads();
  int c0 = (l >> 4) ^ (l & 7);
  int c1 = ((l >> 4) + 4) ^ (l & 7);
  const int nk = HID_ / 64;
  for (int t = 0; t < nk; t++){
    int cur = t & 1;
    if (t + 1 < nk) STAGE(cur ^ 1, (t + 1) * 64);
    bf16x8 af[2][2], bfr[2][2];
    #pragma unroll
    for (int mi = 0; mi < 2; mi++){
      int rbase = (wr * 32 + mi * 16 + (l & 15)) * 64;
      af[mi][0] = *(const bf16x8*)&As[cur][rbase + 8 * c0];
      af[mi][1] = *(const bf16x8*)&As[cur][rbase + 8 * c1];
    }
    #pragma unroll
    for (int ni = 0; ni < 2; ni++){
      int rbase = (wc * 32 + ni * 16 + (l & 15)) * 64;
      bfr[ni][0] = *(const bf16x8*)&Bs[cur][rbase + 8 * c0];
      bfr[ni][1] = *(const bf16x8*)&Bs[cur][rbase + 8 * c1];
    }
    #pragma unroll
    for (int mi = 0; mi < 2; mi++)
      #pragma unroll
      for (int ni = 0; ni < 2; ni++){
        acc[mi][ni] = __builtin_amdgcn_mfma_f32_16x16x32_bf16(af[mi][0], bfr[ni][0], acc[mi][ni], 0, 0, 0);
        acc[mi][ni] = __builtin_amdgcn_mfma_f32_16x16x32_bf16(af[mi][1], bfr[ni][1], acc[mi][ni], 0, 0, 0);
      }
    __syncthreads();
  }
  int r4 = (l >> 4) * 4, cc = l & 15;
  #pragma unroll
  for (int mi = 0; mi < 2; mi++){
    #pragma unroll
    for (int r = 0; r < 4; r++){
      int rowl = mt * 64 + wr * 32 + mi * 16 + r4 + r;
      if (rowl < cnt){
        int tok = order[off + rowl];
        float pv = pc[tok];
        #pragma unroll
        for (int ni = 0; ni < 2; ni++){
          int col = nt * 64 + wc * 32 + ni * 16 + cc;
          float v = acc[mi][ni][r] + b2[e * D_ + col];
          out[(size_t)tok * D_ + col] = x2[(size_t)tok * D_ + col] + pv * v;
        }
      }
    }
  }
}

extern "C" void kernel_launch(void* const* d_in, const int* in_sizes, int n_in,
                              void* d_out, int out_size, void* d_ws, size_t ws_size,
                              hipStream_t stream){
  const float* x         = (const float*)d_in[0];
  const float* ln1_w     = (const float*)d_in[1];
  const float* ln1_b     = (const float*)d_in[2];
  const float* in_proj_w = (const float*)d_in[3];
  const float* in_proj_b = (const float*)d_in[4];
  const float* out_proj_w= (const float*)d_in[5];
  const float* out_proj_b= (const float*)d_in[6];
  const float* ln2_w     = (const float*)d_in[7];
  const float* ln2_b     = (const float*)d_in[8];
  const float* Wg        = (const float*)d_in[9];
  const float* bg        = (const float*)d_in[10];
  const float* We        = (const float*)d_in[11];
  const float* be        = (const float*)d_in[12];
  const float* W1        = (const float*)d_in[13];
  const float* b1        = (const float*)d_in[14];
  const float* W2        = (const float*)d_in[15];
  const float* b2        = (const float*)d_in[16];
  float* out = (float*)d_out;

  char* ws = (char*)d_ws;
  size_t off = 0;
  auto alloc = [&](size_t bytes) -> char* {
    char* p = ws + off;
    off += (bytes + 255) & ~(size_t)255;
    return p;
  };
  u16*   inpTh = (u16*)  alloc((size_t)3 * D_ * D_ * 2);  // 3538944 B
  u16*   inpTl = (u16*)  alloc((size_t)3 * D_ * D_ * 2);
  u16*   outpTh= (u16*)  alloc((size_t)D_ * D_ * 2);
  u16*   outpTl= (u16*)  alloc((size_t)D_ * D_ * 2);
  u16*   W1t  = (u16*)  alloc((size_t)E_ * HID_ * D_ * 2);
  u16*   W2t  = (u16*)  alloc((size_t)E_ * D_ * HID_ * 2);
  u16*   qkvh = (u16*)  alloc((size_t)NTOK * 3 * D_ * 2);
  u16*   qkvl = (u16*)  alloc((size_t)NTOK * 3 * D_ * 2);
  u16*   h1h  = (u16*)  alloc((size_t)NTOK * D_ * 2);
  u16*   h1l  = (u16*)  alloc((size_t)NTOK * D_ * 2);
  u16*   vth  = (u16*)  alloc((size_t)B_ * NH_ * DH_ * S_ * 2);
  u16*   vtl  = (u16*)  alloc((size_t)B_ * NH_ * DH_ * S_ * 2);
  float* x2   = (float*)alloc((size_t)NTOK * D_ * 4);
  u16*   h2   = (u16*)  alloc((size_t)NTOK * D_ * 2);
  int*   flat = (int*)  alloc(NTOK * 4);
  float* pc   = (float*)alloc(NTOK * 4);
  int*   order= (int*)  alloc(NTOK * 4);
  int*   moeI = (int*)  alloc(32 * 4);
  // aliases (lifetimes disjoint, verified sequential):
  float* po0  = (float*)h1h;                       // 6291456 B over h1h+h1l
  float* po1  = (float*)inpTh;                     // 6291456 B over inpTh+inpTl
  float* pmArr= (float*)((char*)inpTh + 6291456);
  float* plArr= (float*)((char*)inpTh + 6291456 + 196608);
  u16*   attnh= qkvh;
  u16*   attnl= qkvl;
  float* h2f  = (float*)qkvh;
  u16*   hid  = (u16*)qkvl;

  // fused weight prep
  k_prep<<<dim3(20736), dim3(256), 0, stream>>>(
      in_proj_w, out_proj_w, W1, W2, inpTh, inpTl, outpTh, outpTl, W1t, W2t);
  // LN1 (split output)
  k_layernorm<<<dim3(NTOK), dim3(256), 0, stream>>>(x, ln1_w, ln1_b, h1h, h1l, (float*)nullptr);
  // QKV (split GEMM -> split output)
  k_gemm3<0><<<dim3(NTOK / 64, 3 * D_ / 64), dim3(256), 0, stream>>>(
      h1h, h1l, inpTh, inpTl, in_proj_b, nullptr, qkvh, qkvl, nullptr, NTOK, 3 * D_, D_);
  // V transpose
  k_transpose_v<<<dim3(DH_ / 32, S_ / 32, B_ * NH_), dim3(32, 8), 0, stream>>>(qkvh, qkvl, vth, vtl);
  // attention split-K partials
  k_attn3<<<dim3(B_ * NH_, S_ / 64, 2), dim3(256), 0, stream>>>(
      qkvh, qkvl, vth, vtl, po0, po1, pmArr, plArr);
  // merge halves -> split bf16 attn (into qkv region)
  k_attn_merge<<<dim3(B_ * NH_, S_ / 64), dim3(256), 0, stream>>>(
      po0, po1, pmArr, plArr, attnh, attnl);
  // out-proj + residual -> x2 (f32)
  k_gemm3<1><<<dim3(NTOK / 64, D_ / 64), dim3(256), 0, stream>>>(
      attnh, attnl, outpTh, outpTl, out_proj_b, x, nullptr, nullptr, x2, NTOK, D_, D_);
  // LN2: bf16 hi for MoE + f32 for router
  k_layernorm<<<dim3(NTOK), dim3(256), 0, stream>>>(x2, ln2_w, ln2_b, h2, (u16*)nullptr, h2f);
  // router + bucketing
  k_router<<<dim3(NTOK / 4), dim3(256), 0, stream>>>(h2f, Wg, bg, We, be, flat, pc);
  k_bucket<<<dim3(1), dim3(1024), 0, stream>>>(flat, moeI, order);
  // grouped expert GEMMs (e = blockIdx.x -> XCD pin)
  k_moe_gemm1<<<dim3(E_, NTOK / 64, HID_ / 64), dim3(256), 0, stream>>>(h2, W1t, b1, order, moeI, hid);
  k_moe_gemm2<<<dim3(E_, NTOK / 64, D_ / 64), dim3(256), 0, stream>>>(hid, W2t, b2, order, moeI, pc, x2, out);
}